// Round 3
// baseline (732.950 us; speedup 1.0000x reference)
//
#include <hip/hip_runtime.h>
#include <hip/hip_bf16.h>

// Problem: B=2, Ccat=128, OUT=64, H=W=256, f32 in/out storage, bf16-grade 2% tol.
// Pipeline:
//   prep: weights -> [tap][oc][ic] bf16; zero stats
//   zhalo: zero the halo border of the padded xcat buffer
//   xpose: x2 NCHW -> padded xcat NHWC lower 64ch
//   upmfma: convT2x2 (MFMA, 4 parity GEMMs) -> padded xcat upper 64ch + planar XPU
//   offconv (MFMA, 128px x 256oc blocks, 4 waves, wave=64px x 128oc, 2-phase
//            K-split; staging via global_load_lds w16 + XOR-swizzle (T2, m201
//            both-sides involution); 52.2KB LDS -> 3 blocks/CU)
//   gather: bilinear deform (planar sources) -> xd NHWC bf16
//   conv1 (MFMA) + bias -> c1o NHWC; stats; bnrelu -> h1 NHWC
//   conv2 (MFMA) + bias -> c2o NHWC; stats; bnrelu+xpose -> d_out NCHW f32
// xcat is PADDED: (B, 258 rows, 264 px, 128 ch) bf16, data at [1..256][1..256],
// halo zeroed once by k_zhalo -> offconv staging needs no bounds checks.
// g_ws: xcat 0..36Mi | off 36..100Mi | xd 100..132Mi | c1o 132..148Mi |
//       h1 148..164Mi | c2o 164..180Mi | Wo/W1/W2 180Mi..+811008 | XPU 181..197Mi

typedef short short8 __attribute__((ext_vector_type(8)));
typedef short short4v __attribute__((ext_vector_type(4)));
typedef float f32x4 __attribute__((ext_vector_type(4)));

__device__ unsigned char g_ws[197u << 20] __attribute__((aligned(256)));
__device__ float g_st[256];

#define OFF_XCAT 0u
#define OFF_OFF  (36u << 20)
#define OFF_XD   (100u << 20)
#define OFF_C1O  (132u << 20)
#define OFF_H1   (148u << 20)
#define OFF_C2O  (164u << 20)
#define OFF_WO   (180u << 20)
#define OFF_W1   ((180u << 20) + 589824u)
#define OFF_W2   ((180u << 20) + 737280u)
#define OFF_XPU  (181u << 20)

// padded xcat geometry (shorts)
#define XROW 264            // px per padded row
#define XRSH (XROW * 128)   // shorts per padded row = 33792

__device__ __forceinline__ float b2f(__hip_bfloat16 v) { return __bfloat162float(v); }
__device__ __forceinline__ short f2b(float v) {
  __hip_bfloat16 h = __float2bfloat16(v); short s; __builtin_memcpy(&s, &h, 2); return s;
}
__device__ __forceinline__ float s2f(short s) {
  __hip_bfloat16 h; __builtin_memcpy(&h, &s, 2); return __bfloat162float(h);
}
__device__ __forceinline__ void gload_lds16(const void* g, void* l) {
  __builtin_amdgcn_global_load_lds(
      (const __attribute__((address_space(1))) void*)g,
      (__attribute__((address_space(3))) void*)l, 16, 0, 0);
}

// ---------- prep: weight transforms (OIHW f32 -> [tap][oc][ic] bf16) + zero stats ----------
__global__ __launch_bounds__(256)
void k_prep(const float* __restrict__ offw, const float* __restrict__ c1w,
            const float* __restrict__ c2w) {
  const int fid = blockIdx.x * 256 + threadIdx.x;
  if (blockIdx.x == 0) g_st[threadIdx.x] = 0.f;
  __hip_bfloat16* Wo = (__hip_bfloat16*)(g_ws + OFF_WO);
  __hip_bfloat16* W1 = (__hip_bfloat16*)(g_ws + OFF_W1);
  __hip_bfloat16* W2 = (__hip_bfloat16*)(g_ws + OFF_W2);
  if (fid < 294912) {            // Wo: (tap*256+oc)*128+ic
    int ic = fid & 127, rest = fid >> 7, oc = rest & 255, tap = rest >> 8;
    Wo[fid] = __float2bfloat16(offw[(oc * 128 + ic) * 9 + tap]);
  } else if (fid < 368640) {     // W1: (tap*64+oc)*128+ic
    int l = fid - 294912;
    int ic = l & 127, rest = l >> 7, oc = rest & 63, tap = rest >> 6;
    W1[l] = __float2bfloat16(c1w[(oc * 128 + ic) * 9 + tap]);
  } else {                       // W2: (tap*64+oc)*64+ic
    int l = fid - 368640;
    int ic = l & 63, rest = l >> 6, oc = rest & 63, tap = rest >> 6;
    W2[l] = __float2bfloat16(c2w[(oc * 64 + ic) * 9 + tap]);
  }
}

// ---------- zhalo: zero padded-xcat halo (rows 0/257 full; rows 1..256 cols 0,257..263) ----------
__global__ __launch_bounds__(256)
void k_zhalo() {
  short* xp = (short*)(g_ws + OFF_XCAT);
  const int u = blockIdx.x * 256 + threadIdx.x;      // 82432 units, grid exact
  const int cg = u & 15;
  const int rest = u >> 4;
  const int p = rest % 2576, b = rest / 2576;
  int row, col;
  if (p < 264) { row = 0; col = p; }
  else if (p < 528) { row = 257; col = p - 264; }
  else { int q = p - 528; row = 1 + (q >> 3); int cs = q & 7; col = cs ? 256 + cs : 0; }
  short8 z = {};
  *(short8*)(xp + (((size_t)(b * 258) + row) * XROW + col) * 128 + cg * 8) = z;
}

// ---------- xpose: x2 NCHW f32 -> padded xcat NHWC bf16 lower 64 channels ----------
__global__ __launch_bounds__(256)
void k_xpose(const float* __restrict__ x2) {
  __shared__ short T[256][72];
  const int t = threadIdx.x;
  const int h = blockIdx.x & 255, b = blockIdx.x >> 8;
  const float* src = x2 + (size_t)(b * 64) * 65536 + h * 256;
  for (int rep = 0; rep < 64; ++rep) {
    int flat = rep * 256 + t, c = flat >> 8, w = flat & 255;
    T[w][c] = f2b(src[(size_t)c * 65536 + w]);
  }
  __syncthreads();
  short* xcat = (short*)(g_ws + OFF_XCAT) +
                (((size_t)(b * 258) + h + 1) * XROW + 1) * 128;
  for (int rep = 0; rep < 8; ++rep) {
    int unit = rep * 256 + t;  // w*8+cg
    int w = unit >> 3, cg = unit & 7;
    *(short8*)(xcat + (size_t)w * 128 + cg * 8) = *(short8*)(&T[w][cg * 8]);
  }
}

// ---------- upmfma: convT(2x2,s2) via 4 parity GEMMs -> padded xcat upper + XPU planar ----------
__global__ __launch_bounds__(256)
void k_upmfma(const float* __restrict__ x1, const float* __restrict__ up_w,
              const float* __restrict__ up_b) {
  __shared__ short W4[4][64][66];   // [k*2+l][o][i]
  __shared__ short X[64][68];       // [ws][i]
  __shared__ short U[2][128][66];   // [k][wl][o]
  __shared__ float BS[64];
  const int t = threadIdx.x;
  const int half = blockIdx.x & 1, hs = (blockIdx.x >> 1) & 127, b = blockIdx.x >> 8;
  for (int rep = 0; rep < 64; ++rep) {
    int flat = rep * 256 + t;
    int i = flat >> 8, rest = flat & 255, o = rest >> 2, kl = rest & 3;
    W4[kl][o][i] = f2b(up_w[flat]);
  }
  if (t < 64) BS[t] = up_b[t];
  const float* x1b = x1 + (size_t)(b * 64) * 16384 + hs * 128 + half * 64;
  for (int rep = 0; rep < 16; ++rep) {
    int flat = rep * 256 + t;
    int i = flat >> 6, ws = flat & 63;
    X[ws][i] = f2b(x1b[(size_t)i * 16384 + ws]);
  }
  __syncthreads();
  const int wv = t >> 6, lane = t & 63, l15 = lane & 15, quad = lane >> 4;
  short8 bf[2];
#pragma unroll
  for (int ks = 0; ks < 2; ++ks)
    bf[ks] = *(const short8*)(&X[wv * 16 + l15][ks * 32 + quad * 8]);
#pragma unroll
  for (int combo = 0; combo < 4; ++combo) {
    const int k = combo >> 1, l = combo & 1;
    f32x4 acc[4] = {};
#pragma unroll
    for (int nt = 0; nt < 4; ++nt)
#pragma unroll
      for (int ks = 0; ks < 2; ++ks) {
        short8 af = *(const short8*)(&W4[combo][nt * 16 + l15][ks * 32 + quad * 8]);
        acc[nt] = __builtin_amdgcn_mfma_f32_16x16x32_bf16(af, bf[ks], acc[nt], 0, 0, 0);
      }
    const int wl = 2 * (wv * 16 + l15) + l;
#pragma unroll
    for (int nt = 0; nt < 4; ++nt) {
      short4v s;
#pragma unroll
      for (int r = 0; r < 4; ++r) s[r] = f2b(acc[nt][r] + BS[nt * 16 + quad * 4 + r]);
      *(short4v*)(&U[k][wl][nt * 16 + quad * 4]) = s;
    }
  }
  __syncthreads();
  short* xcat = (short*)(g_ws + OFF_XCAT);
  short* xpu = (short*)(g_ws + OFF_XPU);
  for (int rep = 0; rep < 8; ++rep) {
    int unit = rep * 256 + t;
    int k = unit >> 10, wl = (unit >> 3) & 127, cg = unit & 7;
    int h = 2 * hs + k, w = half * 128 + wl;
    *(short8*)(xcat + (((size_t)(b * 258) + h + 1) * XROW + w + 1) * 128 + 64 + cg * 8) =
        *(short8*)(&U[k][wl][cg * 8]);
  }
  for (int rep = 0; rep < 8; ++rep) {
    int unit = rep * 256 + t;
    int o = unit >> 5, k = (unit >> 4) & 1, wg = unit & 15;
    int h = 2 * hs + k;
    short8 v;
#pragma unroll
    for (int j = 0; j < 8; ++j) v[j] = U[k][wg * 8 + j][o];
    *(short8*)(xpu + (size_t)(b * 64 + o) * 65536 + h * 256 + half * 128 + wg * 8) = v;
  }
}

// ---------- offconv: 128->256 3x3 MFMA, 2-phase K-split, gload_lds+swizzle staging ----------
// Block = (b, h, wh): 128 px x 256 oc, 256 threads / 4 waves; wave = 64px x 128oc
// (acc[8][4]). Phase p stages ch[64p,64p+64) of a 3-row x 136-px strip via
// global_load_lds dwordx4 (51 instrs/block, no VGPR round-trip, no bounds checks
// thanks to padded xcat). LDS layout linear [r][px][64ch], chunk-XOR swizzle:
// slot c holds global chunk c^(px&7) (pre-swizzled per-lane SOURCE address;
// same XOR on ds_read side -> bank-uniform b128 reads). 52.2KB LDS -> 3 blocks/CU.
__global__ __launch_bounds__(256, 3)
void k_offconv() {
  __shared__ short R[3 * 136 * 64];   // 52224 B
  const short* X = (const short*)(g_ws + OFF_XCAT);
  const __hip_bfloat16* W = (const __hip_bfloat16*)(g_ws + OFF_WO);
  const int t = threadIdx.x;
  const int vb = (blockIdx.x & 7) * 128 + (blockIdx.x >> 3);  // bijective, 1024%8==0
  const int wh = vb & 1, h = (vb >> 1) & 255, b = vb >> 9;
  const int w0 = wh * 128;
  const int wid = t >> 6, lane = t & 63, l15 = lane & 15, quad = lane >> 4;
  const int ocbase = (wid & 1) * 128;
  const int pxb = (wid >> 1) * 64;
  // staging lane map: lane -> (px = 8u+lpx, slot = lcg), source chunk = lcg^(lpx&7)
  const int lpx = lane >> 3, lcg = lane & 7, swz = lcg ^ (lpx & 7);
  // padded rows h..h+2 == actual h-1..h+1; padded col w0.. == actual w0-1..
  const short* srcp = X + (((size_t)(b * 258) + h) * XROW + w0 + lpx) * 128 + swz * 8;
  f32x4 acc[8][4] = {};
  for (int p = 0; p < 2; ++p) {
    if (p) __syncthreads();   // all waves done reading phase 0
    for (int u = wid; u < 51; u += 4) {   // 3 rows x 17 groups of 8 px
      int r = u / 17, g = u - r * 17;
      gload_lds16(srcp + (size_t)r * XRSH + g * 1024 + p * 64,
                  &R[(r * 136 + g * 8) * 64]);
    }
    __syncthreads();
#pragma unroll
    for (int tap = 0; tap < 9; ++tap) {
      const int ky = tap / 3, kx = tap - 3 * ky;
      const __hip_bfloat16* wtap =
          W + ((size_t)tap * 256 + ocbase + l15) * 128 + p * 64 + quad * 8;
      const int sx = ((l15 + kx) & 7) << 3;           // read-side XOR (px&7)<<3
      const short* srow = &R[(ky * 136 + pxb + l15 + kx) * 64];
#pragma unroll
      for (int ics = 0; ics < 2; ++ics) {
        short8 a[8], bf[4];
#pragma unroll
        for (int ot = 0; ot < 8; ++ot)
          a[ot] = *(const short8*)(wtap + ot * 16 * 128 + ics * 32);
#pragma unroll
        for (int pt = 0; pt < 4; ++pt)
          bf[pt] = *(const short8*)(srow + pt * 16 * 64 + ((ics * 32 + quad * 8) ^ sx));
#pragma unroll
        for (int ot = 0; ot < 8; ++ot)
#pragma unroll
          for (int pt = 0; pt < 4; ++pt)
            acc[ot][pt] = __builtin_amdgcn_mfma_f32_16x16x32_bf16(a[ot], bf[pt], acc[ot][pt], 0, 0, 0);
      }
    }
  }
  __hip_bfloat16* out = (__hip_bfloat16*)(g_ws + OFF_OFF);  // NCHW (B,256,256,256)
#pragma unroll
  for (int ot = 0; ot < 8; ++ot)
#pragma unroll
    for (int pt = 0; pt < 4; ++pt)
#pragma unroll
      for (int r = 0; r < 4; ++r) {
        int oc = ocbase + ot * 16 + quad * 4 + r;
        int px = w0 + pxb + pt * 16 + l15;
        out[(((size_t)(b * 256 + oc)) * 256 + h) * 256 + px] =
            __float2bfloat16(acc[ot][pt][r]);
      }
}

// ---------- MFMA implicit-GEMM 3x3 conv (OC=64), 512-block grid ----------
template <int IC>
__global__ __launch_bounds__(256, 2)
void k_convmfma(size_t xoff, size_t woff, const float* __restrict__ bias, size_t ooff) {
  const __hip_bfloat16* X = (const __hip_bfloat16*)(g_ws + xoff);
  const __hip_bfloat16* W = (const __hip_bfloat16*)(g_ws + woff);
  const int t = threadIdx.x;
  const int wv = t >> 6, lane = t & 63, l15 = lane & 15, quad = lane >> 4;
  const int h = blockIdx.x & 255, b = blockIdx.x >> 8;
  const int pixw = wv * 64;
  const int KS = IC / 32;
  f32x4 acc[4][4] = {};
  for (int tap = 0; tap < 9; ++tap) {
    const int ky = tap / 3, kx = tap - 3 * ky;
    const int row = h + ky - 1;
    const bool rowok = (unsigned)row < 256u;
    int pix[4]; bool pok[4];
#pragma unroll
    for (int pt = 0; pt < 4; ++pt) {
      pix[pt] = pixw + pt * 16 + l15 + kx - 1;
      pok[pt] = rowok && (unsigned)pix[pt] < 256u;
    }
    const __hip_bfloat16* wtap = W + ((size_t)tap * 64 + l15) * IC + quad * 8;
    const __hip_bfloat16* xrow = X + (((size_t)(b * 256) + row) * 256) * IC + quad * 8;
#pragma unroll
    for (int ics = 0; ics < KS; ++ics) {
      short8 a[4];
#pragma unroll
      for (int ot = 0; ot < 4; ++ot)
        a[ot] = *(const short8*)(wtap + ot * 16 * IC + ics * 32);
      short8 bf[4];
#pragma unroll
      for (int pt = 0; pt < 4; ++pt) {
        short8 z = {};
        bf[pt] = pok[pt] ? *(const short8*)(xrow + (size_t)pix[pt] * IC + ics * 32) : z;
      }
#pragma unroll
      for (int ot = 0; ot < 4; ++ot)
#pragma unroll
        for (int pt = 0; pt < 4; ++pt)
          acc[ot][pt] = __builtin_amdgcn_mfma_f32_16x16x32_bf16(a[ot], bf[pt], acc[ot][pt], 0, 0, 0);
    }
  }
  __hip_bfloat16* out = (__hip_bfloat16*)(g_ws + ooff);  // NHWC (B,256,256,64)
#pragma unroll
  for (int ot = 0; ot < 4; ++ot) {
    int oc0 = ot * 16 + quad * 4;
    float bv[4];
#pragma unroll
    for (int r = 0; r < 4; ++r) bv[r] = bias[oc0 + r];
#pragma unroll
    for (int pt = 0; pt < 4; ++pt) {
      int px = pixw + pt * 16 + l15;
      short4v s;
#pragma unroll
      for (int r = 0; r < 4; ++r) s[r] = f2b(acc[ot][pt][r] + bv[r]);
      *(short4v*)(out + ((((size_t)(b * 256) + h) * 256 + px) * 64 + oc0)) = s;
    }
  }
}

// ---------- deform gather: planar sources (x2 f32, XPU bf16) -> xd NHWC bf16 ----------
__global__ __launch_bounds__(256)
void k_gather(const float* __restrict__ x2) {
  __shared__ short G[256 * 130];
  const __hip_bfloat16* off = (const __hip_bfloat16*)(g_ws + OFF_OFF);
  const __hip_bfloat16* xpu = (const __hip_bfloat16*)(g_ws + OFF_XPU);
  short* xd = (short*)(g_ws + OFF_XD);
  const int t = threadIdx.x;
  const int hh = blockIdx.x & 255, b = blockIdx.x >> 8;
  const int hp = 2 * (hh & 127) + (t >> 7);
  const int w0e = 2 * (t & 127);
  const int chb = hh >> 7;
  const float fh = (float)hh, fw = (float)t;
  const __hip_bfloat16* offb = off + ((size_t)(b * 256) * 256 + hp) * 256 + w0e;
  const float* x2b = x2 + (size_t)b * 64 * 65536;
  const __hip_bfloat16* xub = xpu + (size_t)b * 64 * 65536;
  for (int c = 0; c < 128; ++c) {
    unsigned ov = *(const unsigned*)(offb + (size_t)(2 * c + chb) * 65536);
    float oy = __uint_as_float((ov & 0xffffu) << 16);
    float ox = __uint_as_float((ov >> 16) << 16);
    float cy = fminf(fmaxf(oy + fh, 0.f), 255.f);
    float cx = fminf(fmaxf(ox + fw, 0.f), 255.f);
    float y0f = floorf(cy), x0f = floorf(cx);
    int y0 = (int)y0f, x0 = (int)x0f;
    int y1 = (int)ceilf(cy), x1 = (int)ceilf(cx);
    float v00, v10, v01, v11;
    if (c < 64) {
      const float* pl = x2b + (size_t)c * 65536;
      v00 = pl[y0 * 256 + x0]; v10 = pl[y1 * 256 + x0];
      v01 = pl[y0 * 256 + x1]; v11 = pl[y1 * 256 + x1];
    } else {
      const __hip_bfloat16* pl = xub + (size_t)(c - 64) * 65536;
      v00 = b2f(pl[y0 * 256 + x0]); v10 = b2f(pl[y1 * 256 + x0]);
      v01 = b2f(pl[y0 * 256 + x1]); v11 = b2f(pl[y1 * 256 + x1]);
    }
    float wy = cy - y0f, wx = cx - x0f;
    float vt = v00 + (v10 - v00) * wy;
    float vb = v01 + (v11 - v01) * wy;
    G[t * 130 + c] = f2b(vt + (vb - vt) * wx);
  }
  __syncthreads();
  const size_t dst = (size_t)(b * 256 + hh) * 256 * 128;
  for (int it = 0; it < 16; ++it) {
    int g = it * 256 + t;
    *(short8*)(xd + dst + (size_t)g * 8) = *(short8*)(&G[(g >> 4) * 130 + (g & 15) * 8]);
  }
}

// ---------- BN stats: NHWC bf16 (64 ch), coalesced short8 reads ----------
template <int SO>
__global__ __launch_bounds__(256)
void k_stats(size_t xoff) {
  const __hip_bfloat16* x = (const __hip_bfloat16*)(g_ws + xoff);
  __shared__ float P[256][9], P2[256][9];
  const int t = threadIdx.x;
  const int c0 = (t & 7) * 8;
  const int pg = t >> 3;
  float s[8] = {}, s2[8] = {};
  const size_t base = (size_t)blockIdx.x * 512;
  for (int i = 0; i < 16; ++i) {
    size_t p = base + pg + (size_t)i * 32;
    short8 v = *(const short8*)(x + p * 64 + c0);
#pragma unroll
    for (int j = 0; j < 8; ++j) {
      float f = s2f(v[j]);
      s[j] += f; s2[j] = fmaf(f, f, s2[j]);
    }
  }
#pragma unroll
  for (int j = 0; j < 8; ++j) { P[t][j] = s[j]; P2[t][j] = s2[j]; }
  __syncthreads();
  if (t < 64) {
    int cg = t >> 3, j = t & 7;
    float a = 0.f, a2 = 0.f;
    for (int kk = 0; kk < 32; ++kk) { a += P[kk * 8 + cg][j]; a2 += P2[kk * 8 + cg][j]; }
    atomicAdd(&g_st[SO + t], a);
    atomicAdd(&g_st[SO + 64 + t], a2);
  }
}

template <int SO>
__global__ void k_finstat() {
  int c = threadIdx.x;
  if (c < 64) {
    float m = g_st[SO + c] * (1.f / 131072.f);
    float v = g_st[SO + 64 + c] * (1.f / 131072.f) - m * m;
    g_st[SO + c] = m;
    g_st[SO + 64 + c] = rsqrtf(v + 1e-5f);
  }
}

// ---------- BN apply + ReLU: c1o NHWC -> h1 NHWC bf16 ----------
__global__ __launch_bounds__(256)
void k_bnrelu1(const float* __restrict__ g, const float* __restrict__ be) {
  const __hip_bfloat16* x = (const __hip_bfloat16*)(g_ws + OFF_C1O);
  __hip_bfloat16* o = (__hip_bfloat16*)(g_ws + OFF_H1);
  size_t idx = ((size_t)blockIdx.x * 256 + threadIdx.x) * 8;
  int c0 = (int)(idx & 63);
  short8 v = *(const short8*)(x + idx);
  short8 r;
#pragma unroll
  for (int j = 0; j < 8; ++j) {
    int c = c0 + j;
    float f = (s2f(v[j]) - g_st[c]) * g_st[64 + c] * g[c] + be[c];
    r[j] = f2b(fmaxf(f, 0.f));
  }
  *(short8*)(o + idx) = r;
}

// ---------- BN apply + ReLU + NHWC->NCHW f32 to d_out ----------
__global__ __launch_bounds__(256)
void k_bnrelu2(const float* __restrict__ g, const float* __restrict__ be,
               float* __restrict__ dout) {
  __shared__ float T[64 * 257];
  const __hip_bfloat16* x = (const __hip_bfloat16*)(g_ws + OFF_C2O);
  const int t = threadIdx.x;
  const int h = blockIdx.x & 255, b = blockIdx.x >> 8;
  const __hip_bfloat16* px = x + (((size_t)(b * 256) + h) * 256 + t) * 64;
#pragma unroll
  for (int cg = 0; cg < 8; ++cg) {
    short8 v = *(const short8*)(px + cg * 8);
#pragma unroll
    for (int j = 0; j < 8; ++j) {
      int c = cg * 8 + j;
      float f = (s2f(v[j]) - g_st[128 + c]) * g_st[192 + c] * g[c] + be[c];
      T[c * 257 + t] = fmaxf(f, 0.f);
    }
  }
  __syncthreads();
  for (int rep = 0; rep < 64; ++rep) {
    int flat = rep * 256 + t, c = flat >> 8, w = flat & 255;
    dout[(((size_t)(b * 64 + c)) * 256 + h) * 256 + w] = T[c * 257 + w];
  }
}

extern "C" void kernel_launch(void* const* d_in, const int* in_sizes, int n_in,
                              void* d_out, int out_size, void* d_ws, size_t ws_size,
                              hipStream_t stream) {
  const bool ok = (n_in == 13) &&
                  in_sizes[0] == 2097152 && in_sizes[1] == 8388608 &&
                  in_sizes[2] == 16384 && in_sizes[3] == 64 &&
                  in_sizes[4] == 294912 && in_sizes[5] == 73728 &&
                  in_sizes[9] == 36864 && out_size == 8388608;
  if (!ok) { hipMemsetAsync(d_out, 0x46, (size_t)out_size * 2, stream); return; }

  const float* x1   = (const float*)d_in[0];
  const float* x2   = (const float*)d_in[1];
  const float* up_w = (const float*)d_in[2];
  const float* up_b = (const float*)d_in[3];
  const float* offw = (const float*)d_in[4];
  const float* c1w  = (const float*)d_in[5];
  const float* c1b  = (const float*)d_in[6];
  const float* g1   = (const float*)d_in[7];
  const float* b1   = (const float*)d_in[8];
  const float* c2w  = (const float*)d_in[9];
  const float* c2b  = (const float*)d_in[10];
  const float* g2   = (const float*)d_in[11];
  const float* b2   = (const float*)d_in[12];

  k_prep<<<1584, 256, 0, stream>>>(offw, c1w, c2w);
  k_zhalo<<<322, 256, 0, stream>>>();
  k_xpose<<<512, 256, 0, stream>>>(x2);
  k_upmfma<<<512, 256, 0, stream>>>(x1, up_w, up_b);
  k_offconv<<<1024, 256, 0, stream>>>();
  k_gather<<<512, 256, 0, stream>>>(x2);
  k_convmfma<128><<<512, 256, 0, stream>>>(OFF_XD, OFF_W1, c1b, OFF_C1O);
  k_stats<0><<<256, 256, 0, stream>>>(OFF_C1O);
  k_finstat<0><<<1, 64, 0, stream>>>();
  k_bnrelu1<<<4096, 256, 0, stream>>>(g1, b1);
  k_convmfma<64><<<512, 256, 0, stream>>>(OFF_H1, OFF_W2, c2b, OFF_C2O);
  k_stats<128><<<256, 256, 0, stream>>>(OFF_C2O);
  k_finstat<128><<<1, 64, 0, stream>>>();
  k_bnrelu2<<<512, 256, 0, stream>>>(g2, b2, (float*)d_out);

  (void)d_ws; (void)ws_size;
}

// Round 4
// 531.036 us; speedup vs baseline: 1.3802x; 1.3802x over previous
//
#include <hip/hip_runtime.h>
#include <hip/hip_bf16.h>

// Problem: B=2, Ccat=128, OUT=64, H=W=256, f32 in/out storage, bf16-grade 2% tol.
// Pipeline:
//   prep: weights -> [tap][oc][ic] bf16; zero stats
//   zhalo: zero the halo border of the padded xcat buffer
//   xpose: x2 NCHW -> padded xcat NHWC lower 64ch
//   upmfma: convT2x2 (MFMA, 4 parity GEMMs) -> padded xcat upper 64ch + planar XPU
//   offconv (MFMA, 128px x 256oc blocks, 4 waves, wave=64px x 128oc, 2-phase
//            K-split; staging via global_load_lds w16 + XOR-swizzle (T2, m201
//            both-sides involution); 52.2KB LDS, launch_bounds(256,2))
//   gather: bilinear deform (planar sources) -> xd NHWC bf16
//   conv1 (MFMA) + bias -> c1o NHWC; stats; bnrelu -> h1 NHWC
//   conv2 (MFMA) + bias -> c2o NHWC; stats; bnrelu+xpose -> d_out NCHW f32
// xcat is PADDED: (B, 258 rows, 264 px, 128 ch) bf16, data at [1..256][1..256],
// halo zeroed once by k_zhalo -> offconv staging needs no bounds checks.
// REGISTER BUDGET NOTE (R3 post-mortem): acc[8][4] = 128 AGPR + ~84 VGPR ~ 212
// regs/thread. launch_bounds(256,3) caps at ~170 -> accumulator SPILLED to
// scratch (+650MB HBM writes, dur 165->375us). MUST stay at (256,2) (cap 256).
// g_ws: xcat 0..36Mi | off 36..100Mi | xd 100..132Mi | c1o 132..148Mi |
//       h1 148..164Mi | c2o 164..180Mi | Wo/W1/W2 180Mi..+811008 | XPU 181..197Mi

typedef short short8 __attribute__((ext_vector_type(8)));
typedef short short4v __attribute__((ext_vector_type(4)));
typedef float f32x4 __attribute__((ext_vector_type(4)));

__device__ unsigned char g_ws[197u << 20] __attribute__((aligned(256)));
__device__ float g_st[256];

#define OFF_XCAT 0u
#define OFF_OFF  (36u << 20)
#define OFF_XD   (100u << 20)
#define OFF_C1O  (132u << 20)
#define OFF_H1   (148u << 20)
#define OFF_C2O  (164u << 20)
#define OFF_WO   (180u << 20)
#define OFF_W1   ((180u << 20) + 589824u)
#define OFF_W2   ((180u << 20) + 737280u)
#define OFF_XPU  (181u << 20)

// padded xcat geometry (shorts)
#define XROW 264            // px per padded row
#define XRSH (XROW * 128)   // shorts per padded row = 33792

__device__ __forceinline__ float b2f(__hip_bfloat16 v) { return __bfloat162float(v); }
__device__ __forceinline__ short f2b(float v) {
  __hip_bfloat16 h = __float2bfloat16(v); short s; __builtin_memcpy(&s, &h, 2); return s;
}
__device__ __forceinline__ float s2f(short s) {
  __hip_bfloat16 h; __builtin_memcpy(&h, &s, 2); return __bfloat162float(h);
}
__device__ __forceinline__ void gload_lds16(const void* g, void* l) {
  __builtin_amdgcn_global_load_lds(
      (const __attribute__((address_space(1))) void*)g,
      (__attribute__((address_space(3))) void*)l, 16, 0, 0);
}

// ---------- prep: weight transforms (OIHW f32 -> [tap][oc][ic] bf16) + zero stats ----------
__global__ __launch_bounds__(256)
void k_prep(const float* __restrict__ offw, const float* __restrict__ c1w,
            const float* __restrict__ c2w) {
  const int fid = blockIdx.x * 256 + threadIdx.x;
  if (blockIdx.x == 0) g_st[threadIdx.x] = 0.f;
  __hip_bfloat16* Wo = (__hip_bfloat16*)(g_ws + OFF_WO);
  __hip_bfloat16* W1 = (__hip_bfloat16*)(g_ws + OFF_W1);
  __hip_bfloat16* W2 = (__hip_bfloat16*)(g_ws + OFF_W2);
  if (fid < 294912) {            // Wo: (tap*256+oc)*128+ic
    int ic = fid & 127, rest = fid >> 7, oc = rest & 255, tap = rest >> 8;
    Wo[fid] = __float2bfloat16(offw[(oc * 128 + ic) * 9 + tap]);
  } else if (fid < 368640) {     // W1: (tap*64+oc)*128+ic
    int l = fid - 294912;
    int ic = l & 127, rest = l >> 7, oc = rest & 63, tap = rest >> 6;
    W1[l] = __float2bfloat16(c1w[(oc * 128 + ic) * 9 + tap]);
  } else {                       // W2: (tap*64+oc)*64+ic
    int l = fid - 368640;
    int ic = l & 63, rest = l >> 6, oc = rest & 63, tap = rest >> 6;
    W2[l] = __float2bfloat16(c2w[(oc * 64 + ic) * 9 + tap]);
  }
}

// ---------- zhalo: zero padded-xcat halo (rows 0/257 full; rows 1..256 cols 0,257..263) ----------
__global__ __launch_bounds__(256)
void k_zhalo() {
  short* xp = (short*)(g_ws + OFF_XCAT);
  const int u = blockIdx.x * 256 + threadIdx.x;      // 82432 units, grid exact
  const int cg = u & 15;
  const int rest = u >> 4;
  const int p = rest % 2576, b = rest / 2576;
  int row, col;
  if (p < 264) { row = 0; col = p; }
  else if (p < 528) { row = 257; col = p - 264; }
  else { int q = p - 528; row = 1 + (q >> 3); int cs = q & 7; col = cs ? 256 + cs : 0; }
  short8 z = {};
  *(short8*)(xp + (((size_t)(b * 258) + row) * XROW + col) * 128 + cg * 8) = z;
}

// ---------- xpose: x2 NCHW f32 -> padded xcat NHWC bf16 lower 64 channels ----------
__global__ __launch_bounds__(256)
void k_xpose(const float* __restrict__ x2) {
  __shared__ short T[256][72];
  const int t = threadIdx.x;
  const int h = blockIdx.x & 255, b = blockIdx.x >> 8;
  const float* src = x2 + (size_t)(b * 64) * 65536 + h * 256;
  for (int rep = 0; rep < 64; ++rep) {
    int flat = rep * 256 + t, c = flat >> 8, w = flat & 255;
    T[w][c] = f2b(src[(size_t)c * 65536 + w]);
  }
  __syncthreads();
  short* xcat = (short*)(g_ws + OFF_XCAT) +
                (((size_t)(b * 258) + h + 1) * XROW + 1) * 128;
  for (int rep = 0; rep < 8; ++rep) {
    int unit = rep * 256 + t;  // w*8+cg
    int w = unit >> 3, cg = unit & 7;
    *(short8*)(xcat + (size_t)w * 128 + cg * 8) = *(short8*)(&T[w][cg * 8]);
  }
}

// ---------- upmfma: convT(2x2,s2) via 4 parity GEMMs -> padded xcat upper + XPU planar ----------
__global__ __launch_bounds__(256)
void k_upmfma(const float* __restrict__ x1, const float* __restrict__ up_w,
              const float* __restrict__ up_b) {
  __shared__ short W4[4][64][66];   // [k*2+l][o][i]
  __shared__ short X[64][68];       // [ws][i]
  __shared__ short U[2][128][66];   // [k][wl][o]
  __shared__ float BS[64];
  const int t = threadIdx.x;
  const int half = blockIdx.x & 1, hs = (blockIdx.x >> 1) & 127, b = blockIdx.x >> 8;
  for (int rep = 0; rep < 64; ++rep) {
    int flat = rep * 256 + t;
    int i = flat >> 8, rest = flat & 255, o = rest >> 2, kl = rest & 3;
    W4[kl][o][i] = f2b(up_w[flat]);
  }
  if (t < 64) BS[t] = up_b[t];
  const float* x1b = x1 + (size_t)(b * 64) * 16384 + hs * 128 + half * 64;
  for (int rep = 0; rep < 16; ++rep) {
    int flat = rep * 256 + t;
    int i = flat >> 6, ws = flat & 63;
    X[ws][i] = f2b(x1b[(size_t)i * 16384 + ws]);
  }
  __syncthreads();
  const int wv = t >> 6, lane = t & 63, l15 = lane & 15, quad = lane >> 4;
  short8 bf[2];
#pragma unroll
  for (int ks = 0; ks < 2; ++ks)
    bf[ks] = *(const short8*)(&X[wv * 16 + l15][ks * 32 + quad * 8]);
#pragma unroll
  for (int combo = 0; combo < 4; ++combo) {
    const int k = combo >> 1, l = combo & 1;
    f32x4 acc[4] = {};
#pragma unroll
    for (int nt = 0; nt < 4; ++nt)
#pragma unroll
      for (int ks = 0; ks < 2; ++ks) {
        short8 af = *(const short8*)(&W4[combo][nt * 16 + l15][ks * 32 + quad * 8]);
        acc[nt] = __builtin_amdgcn_mfma_f32_16x16x32_bf16(af, bf[ks], acc[nt], 0, 0, 0);
      }
    const int wl = 2 * (wv * 16 + l15) + l;
#pragma unroll
    for (int nt = 0; nt < 4; ++nt) {
      short4v s;
#pragma unroll
      for (int r = 0; r < 4; ++r) s[r] = f2b(acc[nt][r] + BS[nt * 16 + quad * 4 + r]);
      *(short4v*)(&U[k][wl][nt * 16 + quad * 4]) = s;
    }
  }
  __syncthreads();
  short* xcat = (short*)(g_ws + OFF_XCAT);
  short* xpu = (short*)(g_ws + OFF_XPU);
  for (int rep = 0; rep < 8; ++rep) {
    int unit = rep * 256 + t;
    int k = unit >> 10, wl = (unit >> 3) & 127, cg = unit & 7;
    int h = 2 * hs + k, w = half * 128 + wl;
    *(short8*)(xcat + (((size_t)(b * 258) + h + 1) * XROW + w + 1) * 128 + 64 + cg * 8) =
        *(short8*)(&U[k][wl][cg * 8]);
  }
  for (int rep = 0; rep < 8; ++rep) {
    int unit = rep * 256 + t;
    int o = unit >> 5, k = (unit >> 4) & 1, wg = unit & 15;
    int h = 2 * hs + k;
    short8 v;
#pragma unroll
    for (int j = 0; j < 8; ++j) v[j] = U[k][wg * 8 + j][o];
    *(short8*)(xpu + (size_t)(b * 64 + o) * 65536 + h * 256 + half * 128 + wg * 8) = v;
  }
}

// ---------- offconv: 128->256 3x3 MFMA, 2-phase K-split, gload_lds+swizzle staging ----------
// Block = (b, h, wh): 128 px x 256 oc, 256 threads / 4 waves; wave = 64px x 128oc
// (acc[8][4]). Phase p stages ch[64p,64p+64) of a 3-row x 136-px strip via
// global_load_lds dwordx4 (51 instrs/block/phase, no VGPR round-trip, no bounds
// checks thanks to padded xcat). LDS layout linear [r][px][64ch], chunk-XOR
// swizzle: slot c holds global chunk c^(px&7) (pre-swizzled per-lane SOURCE
// address; same XOR on ds_read side -> bank-uniform b128 reads).
// launch_bounds(256,2): reg cap 256 (~212 used incl. 128-reg acc) — (256,3)
// spilled catastrophically (R3).
__global__ __launch_bounds__(256, 2)
void k_offconv() {
  __shared__ short R[3 * 136 * 64];   // 52224 B
  const short* X = (const short*)(g_ws + OFF_XCAT);
  const __hip_bfloat16* W = (const __hip_bfloat16*)(g_ws + OFF_WO);
  const int t = threadIdx.x;
  const int vb = (blockIdx.x & 7) * 128 + (blockIdx.x >> 3);  // bijective, 1024%8==0
  const int wh = vb & 1, h = (vb >> 1) & 255, b = vb >> 9;
  const int w0 = wh * 128;
  const int wid = t >> 6, lane = t & 63, l15 = lane & 15, quad = lane >> 4;
  const int ocbase = (wid & 1) * 128;
  const int pxb = (wid >> 1) * 64;
  // staging lane map: lane -> (px = 8u+lpx, slot = lcg), source chunk = lcg^(lpx&7)
  const int lpx = lane >> 3, lcg = lane & 7, swz = lcg ^ (lpx & 7);
  // padded rows h..h+2 == actual h-1..h+1; padded col w0.. == actual w0-1..
  const short* srcp = X + (((size_t)(b * 258) + h) * XROW + w0 + lpx) * 128 + swz * 8;
  f32x4 acc[8][4] = {};
  for (int p = 0; p < 2; ++p) {
    if (p) __syncthreads();   // all waves done reading phase 0
    for (int u = wid; u < 51; u += 4) {   // 3 rows x 17 groups of 8 px
      int r = u / 17, g = u - r * 17;
      gload_lds16(srcp + (size_t)r * XRSH + g * 1024 + p * 64,
                  &R[(r * 136 + g * 8) * 64]);
    }
    __syncthreads();
#pragma unroll
    for (int tap = 0; tap < 9; ++tap) {
      const int ky = tap / 3, kx = tap - 3 * ky;
      const __hip_bfloat16* wtap =
          W + ((size_t)tap * 256 + ocbase + l15) * 128 + p * 64 + quad * 8;
      const int sx = ((l15 + kx) & 7) << 3;           // read-side XOR (px&7)<<3
      const short* srow = &R[(ky * 136 + pxb + l15 + kx) * 64];
#pragma unroll
      for (int ics = 0; ics < 2; ++ics) {
        short8 a[8], bf[4];
#pragma unroll
        for (int ot = 0; ot < 8; ++ot)
          a[ot] = *(const short8*)(wtap + ot * 16 * 128 + ics * 32);
#pragma unroll
        for (int pt = 0; pt < 4; ++pt)
          bf[pt] = *(const short8*)(srow + pt * 16 * 64 + ((ics * 32 + quad * 8) ^ sx));
#pragma unroll
        for (int ot = 0; ot < 8; ++ot)
#pragma unroll
          for (int pt = 0; pt < 4; ++pt)
            acc[ot][pt] = __builtin_amdgcn_mfma_f32_16x16x32_bf16(a[ot], bf[pt], acc[ot][pt], 0, 0, 0);
      }
    }
  }
  __hip_bfloat16* out = (__hip_bfloat16*)(g_ws + OFF_OFF);  // NCHW (B,256,256,256)
#pragma unroll
  for (int ot = 0; ot < 8; ++ot)
#pragma unroll
    for (int pt = 0; pt < 4; ++pt)
#pragma unroll
      for (int r = 0; r < 4; ++r) {
        int oc = ocbase + ot * 16 + quad * 4 + r;
        int px = w0 + pxb + pt * 16 + l15;
        out[(((size_t)(b * 256 + oc)) * 256 + h) * 256 + px] =
            __float2bfloat16(acc[ot][pt][r]);
      }
}

// ---------- MFMA implicit-GEMM 3x3 conv (OC=64), 512-block grid ----------
template <int IC>
__global__ __launch_bounds__(256, 2)
void k_convmfma(size_t xoff, size_t woff, const float* __restrict__ bias, size_t ooff) {
  const __hip_bfloat16* X = (const __hip_bfloat16*)(g_ws + xoff);
  const __hip_bfloat16* W = (const __hip_bfloat16*)(g_ws + woff);
  const int t = threadIdx.x;
  const int wv = t >> 6, lane = t & 63, l15 = lane & 15, quad = lane >> 4;
  const int h = blockIdx.x & 255, b = blockIdx.x >> 8;
  const int pixw = wv * 64;
  const int KS = IC / 32;
  f32x4 acc[4][4] = {};
  for (int tap = 0; tap < 9; ++tap) {
    const int ky = tap / 3, kx = tap - 3 * ky;
    const int row = h + ky - 1;
    const bool rowok = (unsigned)row < 256u;
    int pix[4]; bool pok[4];
#pragma unroll
    for (int pt = 0; pt < 4; ++pt) {
      pix[pt] = pixw + pt * 16 + l15 + kx - 1;
      pok[pt] = rowok && (unsigned)pix[pt] < 256u;
    }
    const __hip_bfloat16* wtap = W + ((size_t)tap * 64 + l15) * IC + quad * 8;
    const __hip_bfloat16* xrow = X + (((size_t)(b * 256) + row) * 256) * IC + quad * 8;
#pragma unroll
    for (int ics = 0; ics < KS; ++ics) {
      short8 a[4];
#pragma unroll
      for (int ot = 0; ot < 4; ++ot)
        a[ot] = *(const short8*)(wtap + ot * 16 * IC + ics * 32);
      short8 bf[4];
#pragma unroll
      for (int pt = 0; pt < 4; ++pt) {
        short8 z = {};
        bf[pt] = pok[pt] ? *(const short8*)(xrow + (size_t)pix[pt] * IC + ics * 32) : z;
      }
#pragma unroll
      for (int ot = 0; ot < 4; ++ot)
#pragma unroll
        for (int pt = 0; pt < 4; ++pt)
          acc[ot][pt] = __builtin_amdgcn_mfma_f32_16x16x32_bf16(a[ot], bf[pt], acc[ot][pt], 0, 0, 0);
    }
  }
  __hip_bfloat16* out = (__hip_bfloat16*)(g_ws + ooff);  // NHWC (B,256,256,64)
#pragma unroll
  for (int ot = 0; ot < 4; ++ot) {
    int oc0 = ot * 16 + quad * 4;
    float bv[4];
#pragma unroll
    for (int r = 0; r < 4; ++r) bv[r] = bias[oc0 + r];
#pragma unroll
    for (int pt = 0; pt < 4; ++pt) {
      int px = pixw + pt * 16 + l15;
      short4v s;
#pragma unroll
      for (int r = 0; r < 4; ++r) s[r] = f2b(acc[ot][pt][r] + bv[r]);
      *(short4v*)(out + ((((size_t)(b * 256) + h) * 256 + px) * 64 + oc0)) = s;
    }
  }
}

// ---------- deform gather: planar sources (x2 f32, XPU bf16) -> xd NHWC bf16 ----------
__global__ __launch_bounds__(256)
void k_gather(const float* __restrict__ x2) {
  __shared__ short G[256 * 130];
  const __hip_bfloat16* off = (const __hip_bfloat16*)(g_ws + OFF_OFF);
  const __hip_bfloat16* xpu = (const __hip_bfloat16*)(g_ws + OFF_XPU);
  short* xd = (short*)(g_ws + OFF_XD);
  const int t = threadIdx.x;
  const int hh = blockIdx.x & 255, b = blockIdx.x >> 8;
  const int hp = 2 * (hh & 127) + (t >> 7);
  const int w0e = 2 * (t & 127);
  const int chb = hh >> 7;
  const float fh = (float)hh, fw = (float)t;
  const __hip_bfloat16* offb = off + ((size_t)(b * 256) * 256 + hp) * 256 + w0e;
  const float* x2b = x2 + (size_t)b * 64 * 65536;
  const __hip_bfloat16* xub = xpu + (size_t)b * 64 * 65536;
  for (int c = 0; c < 128; ++c) {
    unsigned ov = *(const unsigned*)(offb + (size_t)(2 * c + chb) * 65536);
    float oy = __uint_as_float((ov & 0xffffu) << 16);
    float ox = __uint_as_float((ov >> 16) << 16);
    float cy = fminf(fmaxf(oy + fh, 0.f), 255.f);
    float cx = fminf(fmaxf(ox + fw, 0.f), 255.f);
    float y0f = floorf(cy), x0f = floorf(cx);
    int y0 = (int)y0f, x0 = (int)x0f;
    int y1 = (int)ceilf(cy), x1 = (int)ceilf(cx);
    float v00, v10, v01, v11;
    if (c < 64) {
      const float* pl = x2b + (size_t)c * 65536;
      v00 = pl[y0 * 256 + x0]; v10 = pl[y1 * 256 + x0];
      v01 = pl[y0 * 256 + x1]; v11 = pl[y1 * 256 + x1];
    } else {
      const __hip_bfloat16* pl = xub + (size_t)(c - 64) * 65536;
      v00 = b2f(pl[y0 * 256 + x0]); v10 = b2f(pl[y1 * 256 + x0]);
      v01 = b2f(pl[y0 * 256 + x1]); v11 = b2f(pl[y1 * 256 + x1]);
    }
    float wy = cy - y0f, wx = cx - x0f;
    float vt = v00 + (v10 - v00) * wy;
    float vb = v01 + (v11 - v01) * wy;
    G[t * 130 + c] = f2b(vt + (vb - vt) * wx);
  }
  __syncthreads();
  const size_t dst = (size_t)(b * 256 + hh) * 256 * 128;
  for (int it = 0; it < 16; ++it) {
    int g = it * 256 + t;
    *(short8*)(xd + dst + (size_t)g * 8) = *(short8*)(&G[(g >> 4) * 130 + (g & 15) * 8]);
  }
}

// ---------- BN stats: NHWC bf16 (64 ch), coalesced short8 reads ----------
template <int SO>
__global__ __launch_bounds__(256)
void k_stats(size_t xoff) {
  const __hip_bfloat16* x = (const __hip_bfloat16*)(g_ws + xoff);
  __shared__ float P[256][9], P2[256][9];
  const int t = threadIdx.x;
  const int c0 = (t & 7) * 8;
  const int pg = t >> 3;
  float s[8] = {}, s2[8] = {};
  const size_t base = (size_t)blockIdx.x * 512;
  for (int i = 0; i < 16; ++i) {
    size_t p = base + pg + (size_t)i * 32;
    short8 v = *(const short8*)(x + p * 64 + c0);
#pragma unroll
    for (int j = 0; j < 8; ++j) {
      float f = s2f(v[j]);
      s[j] += f; s2[j] = fmaf(f, f, s2[j]);
    }
  }
#pragma unroll
  for (int j = 0; j < 8; ++j) { P[t][j] = s[j]; P2[t][j] = s2[j]; }
  __syncthreads();
  if (t < 64) {
    int cg = t >> 3, j = t & 7;
    float a = 0.f, a2 = 0.f;
    for (int kk = 0; kk < 32; ++kk) { a += P[kk * 8 + cg][j]; a2 += P2[kk * 8 + cg][j]; }
    atomicAdd(&g_st[SO + t], a);
    atomicAdd(&g_st[SO + 64 + t], a2);
  }
}

template <int SO>
__global__ void k_finstat() {
  int c = threadIdx.x;
  if (c < 64) {
    float m = g_st[SO + c] * (1.f / 131072.f);
    float v = g_st[SO + 64 + c] * (1.f / 131072.f) - m * m;
    g_st[SO + c] = m;
    g_st[SO + 64 + c] = rsqrtf(v + 1e-5f);
  }
}

// ---------- BN apply + ReLU: c1o NHWC -> h1 NHWC bf16 ----------
__global__ __launch_bounds__(256)
void k_bnrelu1(const float* __restrict__ g, const float* __restrict__ be) {
  const __hip_bfloat16* x = (const __hip_bfloat16*)(g_ws + OFF_C1O);
  __hip_bfloat16* o = (__hip_bfloat16*)(g_ws + OFF_H1);
  size_t idx = ((size_t)blockIdx.x * 256 + threadIdx.x) * 8;
  int c0 = (int)(idx & 63);
  short8 v = *(const short8*)(x + idx);
  short8 r;
#pragma unroll
  for (int j = 0; j < 8; ++j) {
    int c = c0 + j;
    float f = (s2f(v[j]) - g_st[c]) * g_st[64 + c] * g[c] + be[c];
    r[j] = f2b(fmaxf(f, 0.f));
  }
  *(short8*)(o + idx) = r;
}

// ---------- BN apply + ReLU + NHWC->NCHW f32 to d_out ----------
__global__ __launch_bounds__(256)
void k_bnrelu2(const float* __restrict__ g, const float* __restrict__ be,
               float* __restrict__ dout) {
  __shared__ float T[64 * 257];
  const __hip_bfloat16* x = (const __hip_bfloat16*)(g_ws + OFF_C2O);
  const int t = threadIdx.x;
  const int h = blockIdx.x & 255, b = blockIdx.x >> 8;
  const __hip_bfloat16* px = x + (((size_t)(b * 256) + h) * 256 + t) * 64;
#pragma unroll
  for (int cg = 0; cg < 8; ++cg) {
    short8 v = *(const short8*)(px + cg * 8);
#pragma unroll
    for (int j = 0; j < 8; ++j) {
      int c = cg * 8 + j;
      float f = (s2f(v[j]) - g_st[128 + c]) * g_st[192 + c] * g[c] + be[c];
      T[c * 257 + t] = fmaxf(f, 0.f);
    }
  }
  __syncthreads();
  for (int rep = 0; rep < 64; ++rep) {
    int flat = rep * 256 + t, c = flat >> 8, w = flat & 255;
    dout[(((size_t)(b * 64 + c)) * 256 + h) * 256 + w] = T[c * 257 + w];
  }
}

extern "C" void kernel_launch(void* const* d_in, const int* in_sizes, int n_in,
                              void* d_out, int out_size, void* d_ws, size_t ws_size,
                              hipStream_t stream) {
  const bool ok = (n_in == 13) &&
                  in_sizes[0] == 2097152 && in_sizes[1] == 8388608 &&
                  in_sizes[2] == 16384 && in_sizes[3] == 64 &&
                  in_sizes[4] == 294912 && in_sizes[5] == 73728 &&
                  in_sizes[9] == 36864 && out_size == 8388608;
  if (!ok) { hipMemsetAsync(d_out, 0x46, (size_t)out_size * 2, stream); return; }

  const float* x1   = (const float*)d_in[0];
  const float* x2   = (const float*)d_in[1];
  const float* up_w = (const float*)d_in[2];
  const float* up_b = (const float*)d_in[3];
  const float* offw = (const float*)d_in[4];
  const float* c1w  = (const float*)d_in[5];
  const float* c1b  = (const float*)d_in[6];
  const float* g1   = (const float*)d_in[7];
  const float* b1   = (const float*)d_in[8];
  const float* c2w  = (const float*)d_in[9];
  const float* c2b  = (const float*)d_in[10];
  const float* g2   = (const float*)d_in[11];
  const float* b2   = (const float*)d_in[12];

  k_prep<<<1584, 256, 0, stream>>>(offw, c1w, c2w);
  k_zhalo<<<322, 256, 0, stream>>>();
  k_xpose<<<512, 256, 0, stream>>>(x2);
  k_upmfma<<<512, 256, 0, stream>>>(x1, up_w, up_b);
  k_offconv<<<1024, 256, 0, stream>>>();
  k_gather<<<512, 256, 0, stream>>>(x2);
  k_convmfma<128><<<512, 256, 0, stream>>>(OFF_XD, OFF_W1, c1b, OFF_C1O);
  k_stats<0><<<256, 256, 0, stream>>>(OFF_C1O);
  k_finstat<0><<<1, 64, 0, stream>>>();
  k_bnrelu1<<<4096, 256, 0, stream>>>(g1, b1);
  k_convmfma<64><<<512, 256, 0, stream>>>(OFF_H1, OFF_W2, c2b, OFF_C2O);
  k_stats<128><<<256, 256, 0, stream>>>(OFF_C2O);
  k_finstat<128><<<1, 64, 0, stream>>>();
  k_bnrelu2<<<512, 256, 0, stream>>>(g2, b2, (float*)d_out);

  (void)d_ws; (void)ws_size;
}

// Round 5
// 442.123 us; speedup vs baseline: 1.6578x; 1.2011x over previous
//
#include <hip/hip_runtime.h>
#include <hip/hip_bf16.h>

// Problem: B=2, Ccat=128, OUT=64, H=W=256, f32 in/out storage, bf16-grade 2% tol.
// Pipeline:
//   prep: weights -> [tap][oc][ic] bf16; zero stats
//   zhalo: zero the halo border of the padded xcat buffer
//   xpose: x2 NCHW -> padded xcat NHWC lower 64ch
//   upmfma: convT2x2 (MFMA, 4 parity GEMMs) -> padded xcat upper 64ch + planar XPU
//   offconv: BOTH-OPERANDS-IN-LDS implicit GEMM (see kernel comment)
//   gather: bilinear deform (planar sources) -> xd NHWC bf16
//   conv1 (MFMA) + bias -> c1o NHWC; stats; bnrelu -> h1 NHWC
//   conv2 (MFMA) + bias -> c2o NHWC; stats; bnrelu+xpose -> d_out NCHW f32
// xcat is PADDED: (B, 258 rows, 264 px, 128 ch) bf16, data at [1..256][1..256],
// halo zeroed once by k_zhalo -> offconv staging needs no bounds checks.
// REGISTER BUDGET (R1/R3 post-mortems): acc[8][4]=128 + ~80 live/addr ~ 210
// regs/thread -> needs cap 256 (2 waves/SIMD). Caps of 128/170 SPILL the
// accumulator (symmetric FETCH/WRITE inflation, 2-4x slowdown).
// g_ws: xcat 0..36Mi | off 36..100Mi | xd 100..132Mi | c1o 132..148Mi |
//       h1 148..164Mi | c2o 164..180Mi | Wo/W1/W2 180Mi..+811008 | XPU 181..197Mi

typedef short short8 __attribute__((ext_vector_type(8)));
typedef short short4v __attribute__((ext_vector_type(4)));
typedef float f32x4 __attribute__((ext_vector_type(4)));

__device__ unsigned char g_ws[197u << 20] __attribute__((aligned(256)));
__device__ float g_st[256];

#define OFF_XCAT 0u
#define OFF_OFF  (36u << 20)
#define OFF_XD   (100u << 20)
#define OFF_C1O  (132u << 20)
#define OFF_H1   (148u << 20)
#define OFF_C2O  (164u << 20)
#define OFF_WO   (180u << 20)
#define OFF_W1   ((180u << 20) + 589824u)
#define OFF_W2   ((180u << 20) + 737280u)
#define OFF_XPU  (181u << 20)

// padded xcat geometry (shorts)
#define XROW 264            // px per padded row
#define XRSH (XROW * 128)   // shorts per padded row = 33792

__device__ __forceinline__ float b2f(__hip_bfloat16 v) { return __bfloat162float(v); }
__device__ __forceinline__ short f2b(float v) {
  __hip_bfloat16 h = __float2bfloat16(v); short s; __builtin_memcpy(&s, &h, 2); return s;
}
__device__ __forceinline__ float s2f(short s) {
  __hip_bfloat16 h; __builtin_memcpy(&h, &s, 2); return __bfloat162float(h);
}
__device__ __forceinline__ void gload_lds16(const void* g, void* l) {
  __builtin_amdgcn_global_load_lds(
      (const __attribute__((address_space(1))) void*)g,
      (__attribute__((address_space(3))) void*)l, 16, 0, 0);
}

// ---------- prep: weight transforms (OIHW f32 -> [tap][oc][ic] bf16) + zero stats ----------
__global__ __launch_bounds__(256)
void k_prep(const float* __restrict__ offw, const float* __restrict__ c1w,
            const float* __restrict__ c2w) {
  const int fid = blockIdx.x * 256 + threadIdx.x;
  if (blockIdx.x == 0) g_st[threadIdx.x] = 0.f;
  __hip_bfloat16* Wo = (__hip_bfloat16*)(g_ws + OFF_WO);
  __hip_bfloat16* W1 = (__hip_bfloat16*)(g_ws + OFF_W1);
  __hip_bfloat16* W2 = (__hip_bfloat16*)(g_ws + OFF_W2);
  if (fid < 294912) {            // Wo: (tap*256+oc)*128+ic
    int ic = fid & 127, rest = fid >> 7, oc = rest & 255, tap = rest >> 8;
    Wo[fid] = __float2bfloat16(offw[(oc * 128 + ic) * 9 + tap]);
  } else if (fid < 368640) {     // W1: (tap*64+oc)*128+ic
    int l = fid - 294912;
    int ic = l & 127, rest = l >> 7, oc = rest & 63, tap = rest >> 6;
    W1[l] = __float2bfloat16(c1w[(oc * 128 + ic) * 9 + tap]);
  } else {                       // W2: (tap*64+oc)*64+ic
    int l = fid - 368640;
    int ic = l & 63, rest = l >> 6, oc = rest & 63, tap = rest >> 6;
    W2[l] = __float2bfloat16(c2w[(oc * 64 + ic) * 9 + tap]);
  }
}

// ---------- zhalo: zero padded-xcat halo (rows 0/257 full; rows 1..256 cols 0,257..263) ----------
__global__ __launch_bounds__(256)
void k_zhalo() {
  short* xp = (short*)(g_ws + OFF_XCAT);
  const int u = blockIdx.x * 256 + threadIdx.x;      // 82432 units, grid exact
  const int cg = u & 15;
  const int rest = u >> 4;
  const int p = rest % 2576, b = rest / 2576;
  int row, col;
  if (p < 264) { row = 0; col = p; }
  else if (p < 528) { row = 257; col = p - 264; }
  else { int q = p - 528; row = 1 + (q >> 3); int cs = q & 7; col = cs ? 256 + cs : 0; }
  short8 z = {};
  *(short8*)(xp + (((size_t)(b * 258) + row) * XROW + col) * 128 + cg * 8) = z;
}

// ---------- xpose: x2 NCHW f32 -> padded xcat NHWC bf16 lower 64 channels ----------
__global__ __launch_bounds__(256)
void k_xpose(const float* __restrict__ x2) {
  __shared__ short T[256][72];
  const int t = threadIdx.x;
  const int h = blockIdx.x & 255, b = blockIdx.x >> 8;
  const float* src = x2 + (size_t)(b * 64) * 65536 + h * 256;
  for (int rep = 0; rep < 64; ++rep) {
    int flat = rep * 256 + t, c = flat >> 8, w = flat & 255;
    T[w][c] = f2b(src[(size_t)c * 65536 + w]);
  }
  __syncthreads();
  short* xcat = (short*)(g_ws + OFF_XCAT) +
                (((size_t)(b * 258) + h + 1) * XROW + 1) * 128;
  for (int rep = 0; rep < 8; ++rep) {
    int unit = rep * 256 + t;  // w*8+cg
    int w = unit >> 3, cg = unit & 7;
    *(short8*)(xcat + (size_t)w * 128 + cg * 8) = *(short8*)(&T[w][cg * 8]);
  }
}

// ---------- upmfma: convT(2x2,s2) via 4 parity GEMMs -> padded xcat upper + XPU planar ----------
__global__ __launch_bounds__(256)
void k_upmfma(const float* __restrict__ x1, const float* __restrict__ up_w,
              const float* __restrict__ up_b) {
  __shared__ short W4[4][64][66];   // [k*2+l][o][i]
  __shared__ short X[64][68];       // [ws][i]
  __shared__ short U[2][128][66];   // [k][wl][o]
  __shared__ float BS[64];
  const int t = threadIdx.x;
  const int half = blockIdx.x & 1, hs = (blockIdx.x >> 1) & 127, b = blockIdx.x >> 8;
  for (int rep = 0; rep < 64; ++rep) {
    int flat = rep * 256 + t;
    int i = flat >> 8, rest = flat & 255, o = rest >> 2, kl = rest & 3;
    W4[kl][o][i] = f2b(up_w[flat]);
  }
  if (t < 64) BS[t] = up_b[t];
  const float* x1b = x1 + (size_t)(b * 64) * 16384 + hs * 128 + half * 64;
  for (int rep = 0; rep < 16; ++rep) {
    int flat = rep * 256 + t;
    int i = flat >> 6, ws = flat & 63;
    X[ws][i] = f2b(x1b[(size_t)i * 16384 + ws]);
  }
  __syncthreads();
  const int wv = t >> 6, lane = t & 63, l15 = lane & 15, quad = lane >> 4;
  short8 bf[2];
#pragma unroll
  for (int ks = 0; ks < 2; ++ks)
    bf[ks] = *(const short8*)(&X[wv * 16 + l15][ks * 32 + quad * 8]);
#pragma unroll
  for (int combo = 0; combo < 4; ++combo) {
    const int k = combo >> 1, l = combo & 1;
    f32x4 acc[4] = {};
#pragma unroll
    for (int nt = 0; nt < 4; ++nt)
#pragma unroll
      for (int ks = 0; ks < 2; ++ks) {
        short8 af = *(const short8*)(&W4[combo][nt * 16 + l15][ks * 32 + quad * 8]);
        acc[nt] = __builtin_amdgcn_mfma_f32_16x16x32_bf16(af, bf[ks], acc[nt], 0, 0, 0);
      }
    const int wl = 2 * (wv * 16 + l15) + l;
#pragma unroll
    for (int nt = 0; nt < 4; ++nt) {
      short4v s;
#pragma unroll
      for (int r = 0; r < 4; ++r) s[r] = f2b(acc[nt][r] + BS[nt * 16 + quad * 4 + r]);
      *(short4v*)(&U[k][wl][nt * 16 + quad * 4]) = s;
    }
  }
  __syncthreads();
  short* xcat = (short*)(g_ws + OFF_XCAT);
  short* xpu = (short*)(g_ws + OFF_XPU);
  for (int rep = 0; rep < 8; ++rep) {
    int unit = rep * 256 + t;
    int k = unit >> 10, wl = (unit >> 3) & 127, cg = unit & 7;
    int h = 2 * hs + k, w = half * 128 + wl;
    *(short8*)(xcat + (((size_t)(b * 258) + h + 1) * XROW + w + 1) * 128 + 64 + cg * 8) =
        *(short8*)(&U[k][wl][cg * 8]);
  }
  for (int rep = 0; rep < 8; ++rep) {
    int unit = rep * 256 + t;
    int o = unit >> 5, k = (unit >> 4) & 1, wg = unit & 15;
    int h = 2 * hs + k;
    short8 v;
#pragma unroll
    for (int j = 0; j < 8; ++j) v[j] = U[k][wg * 8 + j][o];
    *(short8*)(xpu + (size_t)(b * 64 + o) * 65536 + h * 256 + half * 128 + wg * 8) = v;
  }
}

// ---------- offconv: BOTH-operands-in-LDS implicit GEMM, 256px x 256oc blocks ----------
// Block = (b, h): full output row, 256 px x 256 oc, 512 threads / 8 waves;
// wave = 64px x 128oc (acc[8][4]), waves = 4(px) x 2(oc).
// LDS (131 KB, 1 block/CU, 2 waves/SIMD):
//   Bs: 3 rows x 264 px x 64ch input strip (per K-phase p), R4's proven
//       0-conflict scheme: gload_lds linear dest + chunk-XOR (px&7) involution.
//   As0/As1: 256oc x 32ch weight tiles (one per ics), staged per (tap,ics) via
//       gload_lds; chunk-XOR ((oc+(oc>>2))&3) -> 2-way reads (free per m136).
// Per half-tap interval: 8 A + 4 B ds_read_b128 -> barrier -> stage next A-half
// into the just-freed buffer (latency hides under MFMAs) -> 32 MFMA.
// This removes the 1.2 GB of per-wave global weight streaming that pinned
// R0/R2/R4 at MfmaUtil ~19% (weights now staged once per block = 295 MB total).
__global__ __launch_bounds__(512, 2)
void k_offconv() {
  __shared__ short Bs[3 * 264 * 64];   // 101376 B
  __shared__ short As0[256 * 32];      // 16384 B
  __shared__ short As1[256 * 32];      // 16384 B
  const short* X = (const short*)(g_ws + OFF_XCAT);
  const __hip_bfloat16* W = (const __hip_bfloat16*)(g_ws + OFF_WO);
  const int t = threadIdx.x;
  const int vb = (int)((blockIdx.x & 7) * 64 + (blockIdx.x >> 3));  // bijective, 512%8==0
  const int h = vb & 255, b = vb >> 8;
  const int wid = t >> 6, lane = t & 63, l15 = lane & 15, quad = lane >> 4;
  const int ocbase = (wid & 1) * 128;
  const int pxb = (wid >> 1) * 64;
  // B staging lane map (R4): unit = 8px x 64ch; lane -> (lpx, slot lcg), src chunk lcg^(lpx&7)
  const int lpx = lane >> 3, lcg = lane & 7;
  const short* bsrc = X + (((size_t)(b * 258) + h) * XROW + lpx) * 128 + (lcg ^ (lpx & 7)) * 8;
  // A staging lane map: unit = 16oc x 32ch; lane = loc*4+lcg4; src chunk lcg4^((loc+(loc>>2))&3)
  const int loc = lane >> 2, lcg4 = lane & 3;
  const __hip_bfloat16* asrc = W + (size_t)loc * 128 + (lcg4 ^ ((loc + (loc >> 2)) & 3)) * 8;
  // A read-side chunk XOR (2-way banked): same involution, g depends on oc&15 = l15 only
  const int ax = (quad ^ ((l15 + (l15 >> 2)) & 3)) << 3;  // shorts
  const int abase = (ocbase + l15) * 32 + ax;
  f32x4 acc[8][4] = {};

#define STAGE_A(TAP, ICS, P, APTR)                                                  \
  {                                                                                 \
    _Pragma("unroll")                                                               \
    for (int k = 0; k < 2; ++k) {                                                   \
      int u = wid * 2 + k;                                                          \
      gload_lds16(asrc + ((size_t)(TAP) * 256 + u * 16) * 128 + (P) * 64 + (ICS) * 32, \
                  &APTR[u * 512]);                                                  \
    }                                                                               \
  }

  for (int p = 0; p < 2; ++p) {
    if (p) __syncthreads();   // all reads of phase-0 LDS done before restaging
    // stage B strip for this phase: 3 rows x 33 units of 8px x 64ch
    for (int u = wid; u < 99; u += 8) {
      int r = u / 33, g = u - r * 33;
      gload_lds16(bsrc + (size_t)r * XRSH + g * 1024 + p * 64, &Bs[(r * 264 + g * 8) * 64]);
    }
    STAGE_A(0, 0, p, As0);
    STAGE_A(0, 1, p, As1);
    __syncthreads();          // drains vmcnt -> Bs + As0 + As1 ready
    for (int tap = 0; tap < 9; ++tap) {
      const int ky = tap / 3, kx = tap - 3 * ky;
      const short* srow = &Bs[(ky * 264 + pxb + l15 + kx) * 64];
      const int sx = ((l15 + kx) & 7) << 3;
      {  // ics = 0
        short8 a[8], bf[4];
#pragma unroll
        for (int ot = 0; ot < 8; ++ot) a[ot] = *(const short8*)(As0 + abase + ot * 512);
#pragma unroll
        for (int pt = 0; pt < 4; ++pt)
          bf[pt] = *(const short8*)(srow + pt * 1024 + ((quad * 8) ^ sx));
        __syncthreads();      // everyone read As0 (own lgkm drained pre-barrier)
        if (tap < 8) STAGE_A(tap + 1, 0, p, As0);
#pragma unroll
        for (int ot = 0; ot < 8; ++ot)
#pragma unroll
          for (int pt = 0; pt < 4; ++pt)
            acc[ot][pt] = __builtin_amdgcn_mfma_f32_16x16x32_bf16(a[ot], bf[pt], acc[ot][pt], 0, 0, 0);
      }
      {  // ics = 1
        short8 a[8], bf[4];
#pragma unroll
        for (int ot = 0; ot < 8; ++ot) a[ot] = *(const short8*)(As1 + abase + ot * 512);
#pragma unroll
        for (int pt = 0; pt < 4; ++pt)
          bf[pt] = *(const short8*)(srow + pt * 1024 + ((32 + quad * 8) ^ sx));
        __syncthreads();
        if (tap < 8) STAGE_A(tap + 1, 1, p, As1);
#pragma unroll
        for (int ot = 0; ot < 8; ++ot)
#pragma unroll
          for (int pt = 0; pt < 4; ++pt)
            acc[ot][pt] = __builtin_amdgcn_mfma_f32_16x16x32_bf16(a[ot], bf[pt], acc[ot][pt], 0, 0, 0);
      }
    }
  }
  __hip_bfloat16* out = (__hip_bfloat16*)(g_ws + OFF_OFF);  // NCHW (B,256,256,256)
#pragma unroll
  for (int ot = 0; ot < 8; ++ot)
#pragma unroll
    for (int pt = 0; pt < 4; ++pt)
#pragma unroll
      for (int r = 0; r < 4; ++r) {
        int oc = ocbase + ot * 16 + quad * 4 + r;
        int px = pxb + pt * 16 + l15;
        out[(((size_t)(b * 256 + oc)) * 256 + h) * 256 + px] =
            __float2bfloat16(acc[ot][pt][r]);
      }
#undef STAGE_A
}

// ---------- MFMA implicit-GEMM 3x3 conv (OC=64), 512-block grid ----------
template <int IC>
__global__ __launch_bounds__(256, 2)
void k_convmfma(size_t xoff, size_t woff, const float* __restrict__ bias, size_t ooff) {
  const __hip_bfloat16* X = (const __hip_bfloat16*)(g_ws + xoff);
  const __hip_bfloat16* W = (const __hip_bfloat16*)(g_ws + woff);
  const int t = threadIdx.x;
  const int wv = t >> 6, lane = t & 63, l15 = lane & 15, quad = lane >> 4;
  const int h = blockIdx.x & 255, b = blockIdx.x >> 8;
  const int pixw = wv * 64;
  const int KS = IC / 32;
  f32x4 acc[4][4] = {};
  for (int tap = 0; tap < 9; ++tap) {
    const int ky = tap / 3, kx = tap - 3 * ky;
    const int row = h + ky - 1;
    const bool rowok = (unsigned)row < 256u;
    int pix[4]; bool pok[4];
#pragma unroll
    for (int pt = 0; pt < 4; ++pt) {
      pix[pt] = pixw + pt * 16 + l15 + kx - 1;
      pok[pt] = rowok && (unsigned)pix[pt] < 256u;
    }
    const __hip_bfloat16* wtap = W + ((size_t)tap * 64 + l15) * IC + quad * 8;
    const __hip_bfloat16* xrow = X + (((size_t)(b * 256) + row) * 256) * IC + quad * 8;
#pragma unroll
    for (int ics = 0; ics < KS; ++ics) {
      short8 a[4];
#pragma unroll
      for (int ot = 0; ot < 4; ++ot)
        a[ot] = *(const short8*)(wtap + ot * 16 * IC + ics * 32);
      short8 bf[4];
#pragma unroll
      for (int pt = 0; pt < 4; ++pt) {
        short8 z = {};
        bf[pt] = pok[pt] ? *(const short8*)(xrow + (size_t)pix[pt] * IC + ics * 32) : z;
      }
#pragma unroll
      for (int ot = 0; ot < 4; ++ot)
#pragma unroll
        for (int pt = 0; pt < 4; ++pt)
          acc[ot][pt] = __builtin_amdgcn_mfma_f32_16x16x32_bf16(a[ot], bf[pt], acc[ot][pt], 0, 0, 0);
    }
  }
  __hip_bfloat16* out = (__hip_bfloat16*)(g_ws + ooff);  // NHWC (B,256,256,64)
#pragma unroll
  for (int ot = 0; ot < 4; ++ot) {
    int oc0 = ot * 16 + quad * 4;
    float bv[4];
#pragma unroll
    for (int r = 0; r < 4; ++r) bv[r] = bias[oc0 + r];
#pragma unroll
    for (int pt = 0; pt < 4; ++pt) {
      int px = pixw + pt * 16 + l15;
      short4v s;
#pragma unroll
      for (int r = 0; r < 4; ++r) s[r] = f2b(acc[ot][pt][r] + bv[r]);
      *(short4v*)(out + ((((size_t)(b * 256) + h) * 256 + px) * 64 + oc0)) = s;
    }
  }
}

// ---------- deform gather: planar sources (x2 f32, XPU bf16) -> xd NHWC bf16 ----------
__global__ __launch_bounds__(256)
void k_gather(const float* __restrict__ x2) {
  __shared__ short G[256 * 130];
  const __hip_bfloat16* off = (const __hip_bfloat16*)(g_ws + OFF_OFF);
  const __hip_bfloat16* xpu = (const __hip_bfloat16*)(g_ws + OFF_XPU);
  short* xd = (short*)(g_ws + OFF_XD);
  const int t = threadIdx.x;
  const int hh = blockIdx.x & 255, b = blockIdx.x >> 8;
  const int hp = 2 * (hh & 127) + (t >> 7);
  const int w0e = 2 * (t & 127);
  const int chb = hh >> 7;
  const float fh = (float)hh, fw = (float)t;
  const __hip_bfloat16* offb = off + ((size_t)(b * 256) * 256 + hp) * 256 + w0e;
  const float* x2b = x2 + (size_t)b * 64 * 65536;
  const __hip_bfloat16* xub = xpu + (size_t)b * 64 * 65536;
  for (int c = 0; c < 128; ++c) {
    unsigned ov = *(const unsigned*)(offb + (size_t)(2 * c + chb) * 65536);
    float oy = __uint_as_float((ov & 0xffffu) << 16);
    float ox = __uint_as_float((ov >> 16) << 16);
    float cy = fminf(fmaxf(oy + fh, 0.f), 255.f);
    float cx = fminf(fmaxf(ox + fw, 0.f), 255.f);
    float y0f = floorf(cy), x0f = floorf(cx);
    int y0 = (int)y0f, x0 = (int)x0f;
    int y1 = (int)ceilf(cy), x1 = (int)ceilf(cx);
    float v00, v10, v01, v11;
    if (c < 64) {
      const float* pl = x2b + (size_t)c * 65536;
      v00 = pl[y0 * 256 + x0]; v10 = pl[y1 * 256 + x0];
      v01 = pl[y0 * 256 + x1]; v11 = pl[y1 * 256 + x1];
    } else {
      const __hip_bfloat16* pl = xub + (size_t)(c - 64) * 65536;
      v00 = b2f(pl[y0 * 256 + x0]); v10 = b2f(pl[y1 * 256 + x0]);
      v01 = b2f(pl[y0 * 256 + x1]); v11 = b2f(pl[y1 * 256 + x1]);
    }
    float wy = cy - y0f, wx = cx - x0f;
    float vt = v00 + (v10 - v00) * wy;
    float vb = v01 + (v11 - v01) * wy;
    G[t * 130 + c] = f2b(vt + (vb - vt) * wx);
  }
  __syncthreads();
  const size_t dst = (size_t)(b * 256 + hh) * 256 * 128;
  for (int it = 0; it < 16; ++it) {
    int g = it * 256 + t;
    *(short8*)(xd + dst + (size_t)g * 8) = *(short8*)(&G[(g >> 4) * 130 + (g & 15) * 8]);
  }
}

// ---------- BN stats: NHWC bf16 (64 ch), coalesced short8 reads ----------
template <int SO>
__global__ __launch_bounds__(256)
void k_stats(size_t xoff) {
  const __hip_bfloat16* x = (const __hip_bfloat16*)(g_ws + xoff);
  __shared__ float P[256][9], P2[256][9];
  const int t = threadIdx.x;
  const int c0 = (t & 7) * 8;
  const int pg = t >> 3;
  float s[8] = {}, s2[8] = {};
  const size_t base = (size_t)blockIdx.x * 512;
  for (int i = 0; i < 16; ++i) {
    size_t p = base + pg + (size_t)i * 32;
    short8 v = *(const short8*)(x + p * 64 + c0);
#pragma unroll
    for (int j = 0; j < 8; ++j) {
      float f = s2f(v[j]);
      s[j] += f; s2[j] = fmaf(f, f, s2[j]);
    }
  }
#pragma unroll
  for (int j = 0; j < 8; ++j) { P[t][j] = s[j]; P2[t][j] = s2[j]; }
  __syncthreads();
  if (t < 64) {
    int cg = t >> 3, j = t & 7;
    float a = 0.f, a2 = 0.f;
    for (int kk = 0; kk < 32; ++kk) { a += P[kk * 8 + cg][j]; a2 += P2[kk * 8 + cg][j]; }
    atomicAdd(&g_st[SO + t], a);
    atomicAdd(&g_st[SO + 64 + t], a2);
  }
}

template <int SO>
__global__ void k_finstat() {
  int c = threadIdx.x;
  if (c < 64) {
    float m = g_st[SO + c] * (1.f / 131072.f);
    float v = g_st[SO + 64 + c] * (1.f / 131072.f) - m * m;
    g_st[SO + c] = m;
    g_st[SO + 64 + c] = rsqrtf(v + 1e-5f);
  }
}

// ---------- BN apply + ReLU: c1o NHWC -> h1 NHWC bf16 ----------
__global__ __launch_bounds__(256)
void k_bnrelu1(const float* __restrict__ g, const float* __restrict__ be) {
  const __hip_bfloat16* x = (const __hip_bfloat16*)(g_ws + OFF_C1O);
  __hip_bfloat16* o = (__hip_bfloat16*)(g_ws + OFF_H1);
  size_t idx = ((size_t)blockIdx.x * 256 + threadIdx.x) * 8;
  int c0 = (int)(idx & 63);
  short8 v = *(const short8*)(x + idx);
  short8 r;
#pragma unroll
  for (int j = 0; j < 8; ++j) {
    int c = c0 + j;
    float f = (s2f(v[j]) - g_st[c]) * g_st[64 + c] * g[c] + be[c];
    r[j] = f2b(fmaxf(f, 0.f));
  }
  *(short8*)(o + idx) = r;
}

// ---------- BN apply + ReLU + NHWC->NCHW f32 to d_out ----------
__global__ __launch_bounds__(256)
void k_bnrelu2(const float* __restrict__ g, const float* __restrict__ be,
               float* __restrict__ dout) {
  __shared__ float T[64 * 257];
  const __hip_bfloat16* x = (const __hip_bfloat16*)(g_ws + OFF_C2O);
  const int t = threadIdx.x;
  const int h = blockIdx.x & 255, b = blockIdx.x >> 8;
  const __hip_bfloat16* px = x + (((size_t)(b * 256) + h) * 256 + t) * 64;
#pragma unroll
  for (int cg = 0; cg < 8; ++cg) {
    short8 v = *(const short8*)(px + cg * 8);
#pragma unroll
    for (int j = 0; j < 8; ++j) {
      int c = cg * 8 + j;
      float f = (s2f(v[j]) - g_st[128 + c]) * g_st[192 + c] * g[c] + be[c];
      T[c * 257 + t] = fmaxf(f, 0.f);
    }
  }
  __syncthreads();
  for (int rep = 0; rep < 64; ++rep) {
    int flat = rep * 256 + t, c = flat >> 8, w = flat & 255;
    dout[(((size_t)(b * 64 + c)) * 256 + h) * 256 + w] = T[c * 257 + w];
  }
}

extern "C" void kernel_launch(void* const* d_in, const int* in_sizes, int n_in,
                              void* d_out, int out_size, void* d_ws, size_t ws_size,
                              hipStream_t stream) {
  const bool ok = (n_in == 13) &&
                  in_sizes[0] == 2097152 && in_sizes[1] == 8388608 &&
                  in_sizes[2] == 16384 && in_sizes[3] == 64 &&
                  in_sizes[4] == 294912 && in_sizes[5] == 73728 &&
                  in_sizes[9] == 36864 && out_size == 8388608;
  if (!ok) { hipMemsetAsync(d_out, 0x46, (size_t)out_size * 2, stream); return; }

  const float* x1   = (const float*)d_in[0];
  const float* x2   = (const float*)d_in[1];
  const float* up_w = (const float*)d_in[2];
  const float* up_b = (const float*)d_in[3];
  const float* offw = (const float*)d_in[4];
  const float* c1w  = (const float*)d_in[5];
  const float* c1b  = (const float*)d_in[6];
  const float* g1   = (const float*)d_in[7];
  const float* b1   = (const float*)d_in[8];
  const float* c2w  = (const float*)d_in[9];
  const float* c2b  = (const float*)d_in[10];
  const float* g2   = (const float*)d_in[11];
  const float* b2   = (const float*)d_in[12];

  k_prep<<<1584, 256, 0, stream>>>(offw, c1w, c2w);
  k_zhalo<<<322, 256, 0, stream>>>();
  k_xpose<<<512, 256, 0, stream>>>(x2);
  k_upmfma<<<512, 256, 0, stream>>>(x1, up_w, up_b);
  k_offconv<<<512, 512, 0, stream>>>();
  k_gather<<<512, 256, 0, stream>>>(x2);
  k_convmfma<128><<<512, 256, 0, stream>>>(OFF_XD, OFF_W1, c1b, OFF_C1O);
  k_stats<0><<<256, 256, 0, stream>>>(OFF_C1O);
  k_finstat<0><<<1, 64, 0, stream>>>();
  k_bnrelu1<<<4096, 256, 0, stream>>>(g1, b1);
  k_convmfma<64><<<512, 256, 0, stream>>>(OFF_H1, OFF_W2, c2b, OFF_C2O);
  k_stats<128><<<256, 256, 0, stream>>>(OFF_C2O);
  k_finstat<128><<<1, 64, 0, stream>>>();
  k_bnrelu2<<<512, 256, 0, stream>>>(g2, b2, (float*)d_out);

  (void)d_ws; (void)ws_size;
}

// Round 6
// 397.160 us; speedup vs baseline: 1.8455x; 1.1132x over previous
//
#include <hip/hip_runtime.h>
#include <hip/hip_bf16.h>

// Problem: B=2, Ccat=128, OUT=64, H=W=256, f32 in/out storage, bf16-grade 2% tol.
// Pipeline:
//   prep: weights -> [tap][oc][ic] bf16; zero stats
//   zhalo: zero the halo border of the padded xcat buffer
//   xpose: x2 NCHW -> padded xcat NHWC lower 64ch
//   upmfma: convT2x2 (MFMA, 4 parity GEMMs) -> padded xcat upper 64ch + planar XPU
//   offconv: BOTH-OPERANDS-IN-LDS implicit GEMM (see kernel comment)
//   gather: bilinear deform, channel-half per block (4 blocks/CU, 4-deep MLP)
//   conv1 (MFMA) + bias -> c1o NHWC; stats; bnrelu -> h1 NHWC
//   conv2 (MFMA) + bias -> c2o NHWC; stats; bnrelu+xpose -> d_out NCHW f32
// xcat is PADDED: (B, 258 rows, 264 px, 128 ch) bf16, data at [1..256][1..256],
// halo zeroed once by k_zhalo -> offconv staging needs no bounds checks.
// REGISTER BUDGET (R1/R3 post-mortems): acc[8][4]=128 + ~80 live/addr ~ 210
// regs/thread -> needs cap 256 (2 waves/SIMD). Caps of 128/170 SPILL the
// accumulator (symmetric FETCH/WRITE inflation, 2-4x slowdown).
// g_ws: xcat 0..36Mi | off 36..100Mi | xd 100..132Mi | c1o 132..148Mi |
//       h1 148..164Mi | c2o 164..180Mi | Wo/W1/W2 180Mi..+811008 | XPU 181..197Mi

typedef short short8 __attribute__((ext_vector_type(8)));
typedef short short4v __attribute__((ext_vector_type(4)));
typedef float f32x4 __attribute__((ext_vector_type(4)));

__device__ unsigned char g_ws[197u << 20] __attribute__((aligned(256)));
__device__ float g_st[256];

#define OFF_XCAT 0u
#define OFF_OFF  (36u << 20)
#define OFF_XD   (100u << 20)
#define OFF_C1O  (132u << 20)
#define OFF_H1   (148u << 20)
#define OFF_C2O  (164u << 20)
#define OFF_WO   (180u << 20)
#define OFF_W1   ((180u << 20) + 589824u)
#define OFF_W2   ((180u << 20) + 737280u)
#define OFF_XPU  (181u << 20)

// padded xcat geometry (shorts)
#define XROW 264            // px per padded row
#define XRSH (XROW * 128)   // shorts per padded row = 33792

__device__ __forceinline__ float b2f(__hip_bfloat16 v) { return __bfloat162float(v); }
__device__ __forceinline__ short f2b(float v) {
  __hip_bfloat16 h = __float2bfloat16(v); short s; __builtin_memcpy(&s, &h, 2); return s;
}
__device__ __forceinline__ float s2f(short s) {
  __hip_bfloat16 h; __builtin_memcpy(&h, &s, 2); return __bfloat162float(h);
}
__device__ __forceinline__ void gload_lds16(const void* g, void* l) {
  __builtin_amdgcn_global_load_lds(
      (const __attribute__((address_space(1))) void*)g,
      (__attribute__((address_space(3))) void*)l, 16, 0, 0);
}

// ---------- prep: weight transforms (OIHW f32 -> [tap][oc][ic] bf16) + zero stats ----------
__global__ __launch_bounds__(256)
void k_prep(const float* __restrict__ offw, const float* __restrict__ c1w,
            const float* __restrict__ c2w) {
  const int fid = blockIdx.x * 256 + threadIdx.x;
  if (blockIdx.x == 0) g_st[threadIdx.x] = 0.f;
  __hip_bfloat16* Wo = (__hip_bfloat16*)(g_ws + OFF_WO);
  __hip_bfloat16* W1 = (__hip_bfloat16*)(g_ws + OFF_W1);
  __hip_bfloat16* W2 = (__hip_bfloat16*)(g_ws + OFF_W2);
  if (fid < 294912) {            // Wo: (tap*256+oc)*128+ic
    int ic = fid & 127, rest = fid >> 7, oc = rest & 255, tap = rest >> 8;
    Wo[fid] = __float2bfloat16(offw[(oc * 128 + ic) * 9 + tap]);
  } else if (fid < 368640) {     // W1: (tap*64+oc)*128+ic
    int l = fid - 294912;
    int ic = l & 127, rest = l >> 7, oc = rest & 63, tap = rest >> 6;
    W1[l] = __float2bfloat16(c1w[(oc * 128 + ic) * 9 + tap]);
  } else {                       // W2: (tap*64+oc)*64+ic
    int l = fid - 368640;
    int ic = l & 63, rest = l >> 6, oc = rest & 63, tap = rest >> 6;
    W2[l] = __float2bfloat16(c2w[(oc * 64 + ic) * 9 + tap]);
  }
}

// ---------- zhalo: zero padded-xcat halo (rows 0/257 full; rows 1..256 cols 0,257..263) ----------
__global__ __launch_bounds__(256)
void k_zhalo() {
  short* xp = (short*)(g_ws + OFF_XCAT);
  const int u = blockIdx.x * 256 + threadIdx.x;      // 82432 units, grid exact
  const int cg = u & 15;
  const int rest = u >> 4;
  const int p = rest % 2576, b = rest / 2576;
  int row, col;
  if (p < 264) { row = 0; col = p; }
  else if (p < 528) { row = 257; col = p - 264; }
  else { int q = p - 528; row = 1 + (q >> 3); int cs = q & 7; col = cs ? 256 + cs : 0; }
  short8 z = {};
  *(short8*)(xp + (((size_t)(b * 258) + row) * XROW + col) * 128 + cg * 8) = z;
}

// ---------- xpose: x2 NCHW f32 -> padded xcat NHWC bf16 lower 64 channels ----------
__global__ __launch_bounds__(256)
void k_xpose(const float* __restrict__ x2) {
  __shared__ short T[256][72];
  const int t = threadIdx.x;
  const int h = blockIdx.x & 255, b = blockIdx.x >> 8;
  const float* src = x2 + (size_t)(b * 64) * 65536 + h * 256;
  for (int rep = 0; rep < 64; ++rep) {
    int flat = rep * 256 + t, c = flat >> 8, w = flat & 255;
    T[w][c] = f2b(src[(size_t)c * 65536 + w]);
  }
  __syncthreads();
  short* xcat = (short*)(g_ws + OFF_XCAT) +
                (((size_t)(b * 258) + h + 1) * XROW + 1) * 128;
  for (int rep = 0; rep < 8; ++rep) {
    int unit = rep * 256 + t;  // w*8+cg
    int w = unit >> 3, cg = unit & 7;
    *(short8*)(xcat + (size_t)w * 128 + cg * 8) = *(short8*)(&T[w][cg * 8]);
  }
}

// ---------- upmfma: convT(2x2,s2) via 4 parity GEMMs -> padded xcat upper + XPU planar ----------
__global__ __launch_bounds__(256)
void k_upmfma(const float* __restrict__ x1, const float* __restrict__ up_w,
              const float* __restrict__ up_b) {
  __shared__ short W4[4][64][66];   // [k*2+l][o][i]
  __shared__ short X[64][68];       // [ws][i]
  __shared__ short U[2][128][66];   // [k][wl][o]
  __shared__ float BS[64];
  const int t = threadIdx.x;
  const int half = blockIdx.x & 1, hs = (blockIdx.x >> 1) & 127, b = blockIdx.x >> 8;
  for (int rep = 0; rep < 64; ++rep) {
    int flat = rep * 256 + t;
    int i = flat >> 8, rest = flat & 255, o = rest >> 2, kl = rest & 3;
    W4[kl][o][i] = f2b(up_w[flat]);
  }
  if (t < 64) BS[t] = up_b[t];
  const float* x1b = x1 + (size_t)(b * 64) * 16384 + hs * 128 + half * 64;
  for (int rep = 0; rep < 16; ++rep) {
    int flat = rep * 256 + t;
    int i = flat >> 6, ws = flat & 63;
    X[ws][i] = f2b(x1b[(size_t)i * 16384 + ws]);
  }
  __syncthreads();
  const int wv = t >> 6, lane = t & 63, l15 = lane & 15, quad = lane >> 4;
  short8 bf[2];
#pragma unroll
  for (int ks = 0; ks < 2; ++ks)
    bf[ks] = *(const short8*)(&X[wv * 16 + l15][ks * 32 + quad * 8]);
#pragma unroll
  for (int combo = 0; combo < 4; ++combo) {
    const int k = combo >> 1, l = combo & 1;
    f32x4 acc[4] = {};
#pragma unroll
    for (int nt = 0; nt < 4; ++nt)
#pragma unroll
      for (int ks = 0; ks < 2; ++ks) {
        short8 af = *(const short8*)(&W4[combo][nt * 16 + l15][ks * 32 + quad * 8]);
        acc[nt] = __builtin_amdgcn_mfma_f32_16x16x32_bf16(af, bf[ks], acc[nt], 0, 0, 0);
      }
    const int wl = 2 * (wv * 16 + l15) + l;
#pragma unroll
    for (int nt = 0; nt < 4; ++nt) {
      short4v s;
#pragma unroll
      for (int r = 0; r < 4; ++r) s[r] = f2b(acc[nt][r] + BS[nt * 16 + quad * 4 + r]);
      *(short4v*)(&U[k][wl][nt * 16 + quad * 4]) = s;
    }
  }
  __syncthreads();
  short* xcat = (short*)(g_ws + OFF_XCAT);
  short* xpu = (short*)(g_ws + OFF_XPU);
  for (int rep = 0; rep < 8; ++rep) {
    int unit = rep * 256 + t;
    int k = unit >> 10, wl = (unit >> 3) & 127, cg = unit & 7;
    int h = 2 * hs + k, w = half * 128 + wl;
    *(short8*)(xcat + (((size_t)(b * 258) + h + 1) * XROW + w + 1) * 128 + 64 + cg * 8) =
        *(short8*)(&U[k][wl][cg * 8]);
  }
  for (int rep = 0; rep < 8; ++rep) {
    int unit = rep * 256 + t;
    int o = unit >> 5, k = (unit >> 4) & 1, wg = unit & 15;
    int h = 2 * hs + k;
    short8 v;
#pragma unroll
    for (int j = 0; j < 8; ++j) v[j] = U[k][wg * 8 + j][o];
    *(short8*)(xpu + (size_t)(b * 64 + o) * 65536 + h * 256 + half * 128 + wg * 8) = v;
  }
}

// ---------- offconv: BOTH-operands-in-LDS implicit GEMM, 256px x 256oc blocks ----------
// Block = (b, h): full output row, 256 px x 256 oc, 512 threads / 8 waves;
// wave = 64px x 128oc (acc[8][4]), waves = 4(px) x 2(oc).
// LDS (131 KB, 1 block/CU, 2 waves/SIMD):
//   Bs: 3 rows x 264 px x 64ch input strip (per K-phase p), R4's proven
//       0-conflict scheme: gload_lds linear dest + chunk-XOR (px&7) involution.
//   As0/As1: 256oc x 32ch weight tiles (one per ics), staged per (tap,ics) via
//       gload_lds; chunk-XOR ((oc+(oc>>2))&3) -> 2-way reads (free per m136).
// Per half-tap interval: 8 A + 4 B ds_read_b128 -> barrier -> stage next A-half
// into the just-freed buffer (latency hides under MFMAs) -> 32 MFMA.
// This removed the 1.2 GB of per-wave global weight streaming that pinned
// R0/R2/R4 at MfmaUtil ~19% (dur 170 -> <97us, R5).
__global__ __launch_bounds__(512, 2)
void k_offconv() {
  __shared__ short Bs[3 * 264 * 64];   // 101376 B
  __shared__ short As0[256 * 32];      // 16384 B
  __shared__ short As1[256 * 32];      // 16384 B
  const short* X = (const short*)(g_ws + OFF_XCAT);
  const __hip_bfloat16* W = (const __hip_bfloat16*)(g_ws + OFF_WO);
  const int t = threadIdx.x;
  const int vb = (int)((blockIdx.x & 7) * 64 + (blockIdx.x >> 3));  // bijective, 512%8==0
  const int h = vb & 255, b = vb >> 8;
  const int wid = t >> 6, lane = t & 63, l15 = lane & 15, quad = lane >> 4;
  const int ocbase = (wid & 1) * 128;
  const int pxb = (wid >> 1) * 64;
  // B staging lane map (R4): unit = 8px x 64ch; lane -> (lpx, slot lcg), src chunk lcg^(lpx&7)
  const int lpx = lane >> 3, lcg = lane & 7;
  const short* bsrc = X + (((size_t)(b * 258) + h) * XROW + lpx) * 128 + (lcg ^ (lpx & 7)) * 8;
  // A staging lane map: unit = 16oc x 32ch; lane = loc*4+lcg4; src chunk lcg4^((loc+(loc>>2))&3)
  const int loc = lane >> 2, lcg4 = lane & 3;
  const __hip_bfloat16* asrc = W + (size_t)loc * 128 + (lcg4 ^ ((loc + (loc >> 2)) & 3)) * 8;
  // A read-side chunk XOR (2-way banked): same involution, g depends on oc&15 = l15 only
  const int ax = (quad ^ ((l15 + (l15 >> 2)) & 3)) << 3;  // shorts
  const int abase = (ocbase + l15) * 32 + ax;
  f32x4 acc[8][4] = {};

#define STAGE_A(TAP, ICS, P, APTR)                                                  \
  {                                                                                 \
    _Pragma("unroll")                                                               \
    for (int k = 0; k < 2; ++k) {                                                   \
      int u = wid * 2 + k;                                                          \
      gload_lds16(asrc + ((size_t)(TAP) * 256 + u * 16) * 128 + (P) * 64 + (ICS) * 32, \
                  &APTR[u * 512]);                                                  \
    }                                                                               \
  }

  for (int p = 0; p < 2; ++p) {
    if (p) __syncthreads();   // all reads of phase-0 LDS done before restaging
    // stage B strip for this phase: 3 rows x 33 units of 8px x 64ch
    for (int u = wid; u < 99; u += 8) {
      int r = u / 33, g = u - r * 33;
      gload_lds16(bsrc + (size_t)r * XRSH + g * 1024 + p * 64, &Bs[(r * 264 + g * 8) * 64]);
    }
    STAGE_A(0, 0, p, As0);
    STAGE_A(0, 1, p, As1);
    __syncthreads();          // drains vmcnt -> Bs + As0 + As1 ready
    for (int tap = 0; tap < 9; ++tap) {
      const int ky = tap / 3, kx = tap - 3 * ky;
      const short* srow = &Bs[(ky * 264 + pxb + l15 + kx) * 64];
      const int sx = ((l15 + kx) & 7) << 3;
      {  // ics = 0
        short8 a[8], bf[4];
#pragma unroll
        for (int ot = 0; ot < 8; ++ot) a[ot] = *(const short8*)(As0 + abase + ot * 512);
#pragma unroll
        for (int pt = 0; pt < 4; ++pt)
          bf[pt] = *(const short8*)(srow + pt * 1024 + ((quad * 8) ^ sx));
        __syncthreads();      // everyone read As0 (own lgkm drained pre-barrier)
        if (tap < 8) STAGE_A(tap + 1, 0, p, As0);
#pragma unroll
        for (int ot = 0; ot < 8; ++ot)
#pragma unroll
          for (int pt = 0; pt < 4; ++pt)
            acc[ot][pt] = __builtin_amdgcn_mfma_f32_16x16x32_bf16(a[ot], bf[pt], acc[ot][pt], 0, 0, 0);
      }
      {  // ics = 1
        short8 a[8], bf[4];
#pragma unroll
        for (int ot = 0; ot < 8; ++ot) a[ot] = *(const short8*)(As1 + abase + ot * 512);
#pragma unroll
        for (int pt = 0; pt < 4; ++pt)
          bf[pt] = *(const short8*)(srow + pt * 1024 + ((32 + quad * 8) ^ sx));
        __syncthreads();
        if (tap < 8) STAGE_A(tap + 1, 1, p, As1);
#pragma unroll
        for (int ot = 0; ot < 8; ++ot)
#pragma unroll
          for (int pt = 0; pt < 4; ++pt)
            acc[ot][pt] = __builtin_amdgcn_mfma_f32_16x16x32_bf16(a[ot], bf[pt], acc[ot][pt], 0, 0, 0);
      }
    }
  }
  __hip_bfloat16* out = (__hip_bfloat16*)(g_ws + OFF_OFF);  // NCHW (B,256,256,256)
#pragma unroll
  for (int ot = 0; ot < 8; ++ot)
#pragma unroll
    for (int pt = 0; pt < 4; ++pt)
#pragma unroll
      for (int r = 0; r < 4; ++r) {
        int oc = ocbase + ot * 16 + quad * 4 + r;
        int px = pxb + pt * 16 + l15;
        out[(((size_t)(b * 256 + oc)) * 256 + h) * 256 + px] =
            __float2bfloat16(acc[ot][pt][r]);
      }
#undef STAGE_A
}

// ---------- MFMA implicit-GEMM 3x3 conv (OC=64), 512-block grid ----------
template <int IC>
__global__ __launch_bounds__(256, 2)
void k_convmfma(size_t xoff, size_t woff, const float* __restrict__ bias, size_t ooff) {
  const __hip_bfloat16* X = (const __hip_bfloat16*)(g_ws + xoff);
  const __hip_bfloat16* W = (const __hip_bfloat16*)(g_ws + woff);
  const int t = threadIdx.x;
  const int wv = t >> 6, lane = t & 63, l15 = lane & 15, quad = lane >> 4;
  const int h = blockIdx.x & 255, b = blockIdx.x >> 8;
  const int pixw = wv * 64;
  const int KS = IC / 32;
  f32x4 acc[4][4] = {};
  for (int tap = 0; tap < 9; ++tap) {
    const int ky = tap / 3, kx = tap - 3 * ky;
    const int row = h + ky - 1;
    const bool rowok = (unsigned)row < 256u;
    int pix[4]; bool pok[4];
#pragma unroll
    for (int pt = 0; pt < 4; ++pt) {
      pix[pt] = pixw + pt * 16 + l15 + kx - 1;
      pok[pt] = rowok && (unsigned)pix[pt] < 256u;
    }
    const __hip_bfloat16* wtap = W + ((size_t)tap * 64 + l15) * IC + quad * 8;
    const __hip_bfloat16* xrow = X + (((size_t)(b * 256) + row) * 256) * IC + quad * 8;
#pragma unroll
    for (int ics = 0; ics < KS; ++ics) {
      short8 a[4];
#pragma unroll
      for (int ot = 0; ot < 4; ++ot)
        a[ot] = *(const short8*)(wtap + ot * 16 * IC + ics * 32);
      short8 bf[4];
#pragma unroll
      for (int pt = 0; pt < 4; ++pt) {
        short8 z = {};
        bf[pt] = pok[pt] ? *(const short8*)(xrow + (size_t)pix[pt] * IC + ics * 32) : z;
      }
#pragma unroll
      for (int ot = 0; ot < 4; ++ot)
#pragma unroll
        for (int pt = 0; pt < 4; ++pt)
          acc[ot][pt] = __builtin_amdgcn_mfma_f32_16x16x32_bf16(a[ot], bf[pt], acc[ot][pt], 0, 0, 0);
    }
  }
  __hip_bfloat16* out = (__hip_bfloat16*)(g_ws + ooff);  // NHWC (B,256,256,64)
#pragma unroll
  for (int ot = 0; ot < 4; ++ot) {
    int oc0 = ot * 16 + quad * 4;
    float bv[4];
#pragma unroll
    for (int r = 0; r < 4; ++r) bv[r] = bias[oc0 + r];
#pragma unroll
    for (int pt = 0; pt < 4; ++pt) {
      int px = pixw + pt * 16 + l15;
      short4v s;
#pragma unroll
      for (int r = 0; r < 4; ++r) s[r] = f2b(acc[ot][pt][r] + bv[r]);
      *(short4v*)(out + ((((size_t)(b * 256) + h) * 256 + px) * 64 + oc0)) = s;
    }
  }
}

// ---------- deform gather: channel-half per block, 4-deep offset-load pipeline ----------
// Block = (b, hh, half): one output row x 64 channels; grid 1024 -> 4 blocks/CU
// (G LDS 33KB), 4 waves/SIMD (launch_bounds(256,4), VGPR<=128 — R5 ran at 88).
// R5 diagnosis: 2 waves/SIMD + 1-deep {offset load -> 4 gathers} chain = pure
// latency bound (VALUBusy 17%, HBM 18%, MfmaUtil 0). Fix: 2x occupancy + groups
// of 4 channels with all 4 offset dwords preloaded (static-indexed, rule #20)
// -> 4 offset loads + 16 gathers in flight per thread.
// half==0 reads x2 planes (f32), half==1 reads XPU planes (bf16) — the source
// branch is now block-uniform.
__global__ __launch_bounds__(256, 4)
void k_gather(const float* __restrict__ x2) {
  __shared__ short G[256 * 66];   // 33792 B
  const __hip_bfloat16* off = (const __hip_bfloat16*)(g_ws + OFF_OFF);
  const __hip_bfloat16* xpu = (const __hip_bfloat16*)(g_ws + OFF_XPU);
  short* xd = (short*)(g_ws + OFF_XD);
  const int t = threadIdx.x;
  const int half = blockIdx.x & 1;
  const int hh = (blockIdx.x >> 1) & 255, b = blockIdx.x >> 9;
  const int hp = 2 * (hh & 127) + (t >> 7);
  const int w0e = 2 * (t & 127);
  const int chb = hh >> 7;
  const int c0 = half * 64;
  const float fh = (float)hh, fw = (float)t;
  const __hip_bfloat16* offb = off + ((size_t)(b * 256) * 256 + hp) * 256 + w0e +
                               (size_t)(2 * c0 + chb) * 65536;
  if (half == 0) {
    const float* x2b = x2 + (size_t)b * 64 * 65536;
    for (int g4 = 0; g4 < 16; ++g4) {
      unsigned ovv[4];
#pragma unroll
      for (int j = 0; j < 4; ++j)
        ovv[j] = *(const unsigned*)(offb + (size_t)(2 * (g4 * 4 + j)) * 65536);
#pragma unroll
      for (int j = 0; j < 4; ++j) {
        const int crel = g4 * 4 + j;
        unsigned ov = ovv[j];
        float oy = __uint_as_float((ov & 0xffffu) << 16);
        float ox = __uint_as_float((ov >> 16) << 16);
        float cy = fminf(fmaxf(oy + fh, 0.f), 255.f);
        float cx = fminf(fmaxf(ox + fw, 0.f), 255.f);
        float y0f = floorf(cy), x0f = floorf(cx);
        int y0 = (int)y0f, x0 = (int)x0f;
        int y1 = (int)ceilf(cy), x1 = (int)ceilf(cx);
        const float* pl = x2b + (size_t)crel * 65536;
        float v00 = pl[y0 * 256 + x0], v10 = pl[y1 * 256 + x0];
        float v01 = pl[y0 * 256 + x1], v11 = pl[y1 * 256 + x1];
        float wy = cy - y0f, wx = cx - x0f;
        float vt = v00 + (v10 - v00) * wy;
        float vb = v01 + (v11 - v01) * wy;
        G[t * 66 + crel] = f2b(vt + (vb - vt) * wx);
      }
    }
  } else {
    const __hip_bfloat16* xub = xpu + (size_t)b * 64 * 65536;
    for (int g4 = 0; g4 < 16; ++g4) {
      unsigned ovv[4];
#pragma unroll
      for (int j = 0; j < 4; ++j)
        ovv[j] = *(const unsigned*)(offb + (size_t)(2 * (g4 * 4 + j)) * 65536);
#pragma unroll
      for (int j = 0; j < 4; ++j) {
        const int crel = g4 * 4 + j;
        unsigned ov = ovv[j];
        float oy = __uint_as_float((ov & 0xffffu) << 16);
        float ox = __uint_as_float((ov >> 16) << 16);
        float cy = fminf(fmaxf(oy + fh, 0.f), 255.f);
        float cx = fminf(fmaxf(ox + fw, 0.f), 255.f);
        float y0f = floorf(cy), x0f = floorf(cx);
        int y0 = (int)y0f, x0 = (int)x0f;
        int y1 = (int)ceilf(cy), x1 = (int)ceilf(cx);
        const __hip_bfloat16* pl = xub + (size_t)crel * 65536;
        float v00 = b2f(pl[y0 * 256 + x0]), v10 = b2f(pl[y1 * 256 + x0]);
        float v01 = b2f(pl[y0 * 256 + x1]), v11 = b2f(pl[y1 * 256 + x1]);
        float wy = cy - y0f, wx = cx - x0f;
        float vt = v00 + (v10 - v00) * wy;
        float vb = v01 + (v11 - v01) * wy;
        G[t * 66 + crel] = f2b(vt + (vb - vt) * wx);
      }
    }
  }
  __syncthreads();
  const size_t dst = (size_t)(b * 256 + hh) * 256 * 128 + c0;
  for (int it = 0; it < 8; ++it) {
    int g = it * 256 + t;
    *(short8*)(xd + dst + (size_t)(g >> 3) * 128 + (g & 7) * 8) =
        *(short8*)(&G[(g >> 3) * 66 + (g & 7) * 8]);
  }
}

// ---------- BN stats: NHWC bf16 (64 ch), coalesced short8 reads ----------
template <int SO>
__global__ __launch_bounds__(256)
void k_stats(size_t xoff) {
  const __hip_bfloat16* x = (const __hip_bfloat16*)(g_ws + xoff);
  __shared__ float P[256][9], P2[256][9];
  const int t = threadIdx.x;
  const int c0 = (t & 7) * 8;
  const int pg = t >> 3;
  float s[8] = {}, s2[8] = {};
  const size_t base = (size_t)blockIdx.x * 512;
  for (int i = 0; i < 16; ++i) {
    size_t p = base + pg + (size_t)i * 32;
    short8 v = *(const short8*)(x + p * 64 + c0);
#pragma unroll
    for (int j = 0; j < 8; ++j) {
      float f = s2f(v[j]);
      s[j] += f; s2[j] = fmaf(f, f, s2[j]);
    }
  }
#pragma unroll
  for (int j = 0; j < 8; ++j) { P[t][j] = s[j]; P2[t][j] = s2[j]; }
  __syncthreads();
  if (t < 64) {
    int cg = t >> 3, j = t & 7;
    float a = 0.f, a2 = 0.f;
    for (int kk = 0; kk < 32; ++kk) { a += P[kk * 8 + cg][j]; a2 += P2[kk * 8 + cg][j]; }
    atomicAdd(&g_st[SO + t], a);
    atomicAdd(&g_st[SO + 64 + t], a2);
  }
}

template <int SO>
__global__ void k_finstat() {
  int c = threadIdx.x;
  if (c < 64) {
    float m = g_st[SO + c] * (1.f / 131072.f);
    float v = g_st[SO + 64 + c] * (1.f / 131072.f) - m * m;
    g_st[SO + c] = m;
    g_st[SO + 64 + c] = rsqrtf(v + 1e-5f);
  }
}

// ---------- BN apply + ReLU: c1o NHWC -> h1 NHWC bf16 ----------
__global__ __launch_bounds__(256)
void k_bnrelu1(const float* __restrict__ g, const float* __restrict__ be) {
  const __hip_bfloat16* x = (const __hip_bfloat16*)(g_ws + OFF_C1O);
  __hip_bfloat16* o = (__hip_bfloat16*)(g_ws + OFF_H1);
  size_t idx = ((size_t)blockIdx.x * 256 + threadIdx.x) * 8;
  int c0 = (int)(idx & 63);
  short8 v = *(const short8*)(x + idx);
  short8 r;
#pragma unroll
  for (int j = 0; j < 8; ++j) {
    int c = c0 + j;
    float f = (s2f(v[j]) - g_st[c]) * g_st[64 + c] * g[c] + be[c];
    r[j] = f2b(fmaxf(f, 0.f));
  }
  *(short8*)(o + idx) = r;
}

// ---------- BN apply + ReLU + NHWC->NCHW f32 to d_out ----------
__global__ __launch_bounds__(256)
void k_bnrelu2(const float* __restrict__ g, const float* __restrict__ be,
               float* __restrict__ dout) {
  __shared__ float T[64 * 257];
  const __hip_bfloat16* x = (const __hip_bfloat16*)(g_ws + OFF_C2O);
  const int t = threadIdx.x;
  const int h = blockIdx.x & 255, b = blockIdx.x >> 8;
  const __hip_bfloat16* px = x + (((size_t)(b * 256) + h) * 256 + t) * 64;
#pragma unroll
  for (int cg = 0; cg < 8; ++cg) {
    short8 v = *(const short8*)(px + cg * 8);
#pragma unroll
    for (int j = 0; j < 8; ++j) {
      int c = cg * 8 + j;
      float f = (s2f(v[j]) - g_st[128 + c]) * g_st[192 + c] * g[c] + be[c];
      T[c * 257 + t] = fmaxf(f, 0.f);
    }
  }
  __syncthreads();
  for (int rep = 0; rep < 64; ++rep) {
    int flat = rep * 256 + t, c = flat >> 8, w = flat & 255;
    dout[(((size_t)(b * 64 + c)) * 256 + h) * 256 + w] = T[c * 257 + w];
  }
}

extern "C" void kernel_launch(void* const* d_in, const int* in_sizes, int n_in,
                              void* d_out, int out_size, void* d_ws, size_t ws_size,
                              hipStream_t stream) {
  const bool ok = (n_in == 13) &&
                  in_sizes[0] == 2097152 && in_sizes[1] == 8388608 &&
                  in_sizes[2] == 16384 && in_sizes[3] == 64 &&
                  in_sizes[4] == 294912 && in_sizes[5] == 73728 &&
                  in_sizes[9] == 36864 && out_size == 8388608;
  if (!ok) { hipMemsetAsync(d_out, 0x46, (size_t)out_size * 2, stream); return; }

  const float* x1   = (const float*)d_in[0];
  const float* x2   = (const float*)d_in[1];
  const float* up_w = (const float*)d_in[2];
  const float* up_b = (const float*)d_in[3];
  const float* offw = (const float*)d_in[4];
  const float* c1w  = (const float*)d_in[5];
  const float* c1b  = (const float*)d_in[6];
  const float* g1   = (const float*)d_in[7];
  const float* b1   = (const float*)d_in[8];
  const float* c2w  = (const float*)d_in[9];
  const float* c2b  = (const float*)d_in[10];
  const float* g2   = (const float*)d_in[11];
  const float* b2   = (const float*)d_in[12];

  k_prep<<<1584, 256, 0, stream>>>(offw, c1w, c2w);
  k_zhalo<<<322, 256, 0, stream>>>();
  k_xpose<<<512, 256, 0, stream>>>(x2);
  k_upmfma<<<512, 256, 0, stream>>>(x1, up_w, up_b);
  k_offconv<<<512, 512, 0, stream>>>();
  k_gather<<<1024, 256, 0, stream>>>(x2);
  k_convmfma<128><<<512, 256, 0, stream>>>(OFF_XD, OFF_W1, c1b, OFF_C1O);
  k_stats<0><<<256, 256, 0, stream>>>(OFF_C1O);
  k_finstat<0><<<1, 64, 0, stream>>>();
  k_bnrelu1<<<4096, 256, 0, stream>>>(g1, b1);
  k_convmfma<64><<<512, 256, 0, stream>>>(OFF_H1, OFF_W2, c2b, OFF_C2O);
  k_stats<128><<<256, 256, 0, stream>>>(OFF_C2O);
  k_finstat<128><<<1, 64, 0, stream>>>();
  k_bnrelu2<<<512, 256, 0, stream>>>(g2, b2, (float*)d_out);

  (void)d_ws; (void)ws_size;
}

// Round 8
// 339.374 us; speedup vs baseline: 2.1597x; 1.1703x over previous
//
#include <hip/hip_runtime.h>
#include <hip/hip_bf16.h>

// Problem: B=2, Ccat=128, OUT=64, H=W=256, f32 in/out storage, bf16-grade 2% tol.
// Pipeline (9 launches):
//   prep: weights -> [tap][oc][ic] bf16; zero stats; zero ALL padded halos
//   xpose: x2 NCHW -> padded xcat NHWC lower 64ch
//   upmfma: convT2x2 (MFMA, 4 parity GEMMs) -> padded xcat upper 64ch + planar XPU
//   offconv: both-operands-in-LDS implicit GEMM 128->256 (44% MFMA ceiling, R6)
//   gather: bilinear deform -> PADDED xd NHWC bf16 (4 blocks/CU, 4-deep MLP)
//   conv1 = k_conv<128,0>: LDS-staged implicit GEMM + bias + FUSED BN-stats
//   bnrelu1: BN(from raw sums)+ReLU -> PADDED h1
//   conv2 = k_conv<64,128>: same + fused stats
//   bnrelu2: BN+ReLU + NHWC->NCHW f32 -> d_out
// Padded buffers: (B, 258 rows, 264 px, C) bf16, data at [1..256][1..256],
// halos zeroed once by prep -> conv staging needs no bounds checks.
// REGISTER BUDGET (R1/R3): offconv acc[8][4]=128 + ~80 -> needs cap 256
// (launch_bounds .,2). Tighter caps SPILL (symmetric FETCH/WRITE inflation).
// BARRIER-SPACING INVARIANT (R7 post-mortem): a gload_lds restage is visible to
// OTHER waves only after a __syncthreads() that FOLLOWS the issue (own-vmcnt
// drain at the barrier). Single-buffer restage with reads before the next
// barrier is a RACE -> k_conv uses As[2] ping-pong, 1 barrier per tap.
// g_ws: xcat 0..36Mi | off 36..100Mi | xd(pad) 100..134Mi | c1o 134..150Mi |
//  h1(pad) 150..168Mi | c2o 168..184Mi | Wo/W1/W2 184Mi..+811008 | XPU 185..201Mi

typedef short short8 __attribute__((ext_vector_type(8)));
typedef short short4v __attribute__((ext_vector_type(4)));
typedef float f32x4 __attribute__((ext_vector_type(4)));

__device__ unsigned char g_ws[201u << 20] __attribute__((aligned(256)));
__device__ float g_st[256];

#define OFF_XCAT 0u
#define OFF_OFF  (36u << 20)
#define OFF_XD   (100u << 20)
#define OFF_C1O  (134u << 20)
#define OFF_H1   (150u << 20)
#define OFF_C2O  (168u << 20)
#define OFF_WO   (184u << 20)
#define OFF_W1   ((184u << 20) + 589824u)
#define OFF_W2   ((184u << 20) + 737280u)
#define OFF_XPU  (185u << 20)

// padded buffer geometry
#define XROW 264            // px per padded row
#define XRSH (XROW * 128)   // shorts per padded xcat row

__device__ __forceinline__ float b2f(__hip_bfloat16 v) { return __bfloat162float(v); }
__device__ __forceinline__ short f2b(float v) {
  __hip_bfloat16 h = __float2bfloat16(v); short s; __builtin_memcpy(&s, &h, 2); return s;
}
__device__ __forceinline__ float s2f(short s) {
  __hip_bfloat16 h; __builtin_memcpy(&h, &s, 2); return __bfloat162float(h);
}
__device__ __forceinline__ void gload_lds16(const void* g, void* l) {
  __builtin_amdgcn_global_load_lds(
      (const __attribute__((address_space(1))) void*)g,
      (__attribute__((address_space(3))) void*)l, 16, 0, 0);
}

// ---------- prep: weight transforms + zero stats + zero padded halos ----------
// unit map: [0,405504) weights | then xcat halo (82432) | xd halo (82432) |
// h1 halo (41216). total 611584 = 2389 * 256.
__device__ __forceinline__ void halo_zero(short* base, int C, int cshift, int u) {
  const int cg = u & ((1 << cshift) - 1);
  const int rest = u >> cshift;
  const int p = rest % 2576, b = rest / 2576;
  int row, col;
  if (p < 264) { row = 0; col = p; }
  else if (p < 528) { row = 257; col = p - 264; }
  else { int q = p - 528; row = 1 + (q >> 3); int cs = q & 7; col = cs ? 256 + cs : 0; }
  short8 z = {};
  *(short8*)(base + (((size_t)(b * 258) + row) * XROW + col) * C + cg * 8) = z;
}

__global__ __launch_bounds__(256)
void k_prep(const float* __restrict__ offw, const float* __restrict__ c1w,
            const float* __restrict__ c2w) {
  const int fid = blockIdx.x * 256 + threadIdx.x;
  if (blockIdx.x == 0) g_st[threadIdx.x] = 0.f;
  __hip_bfloat16* Wo = (__hip_bfloat16*)(g_ws + OFF_WO);
  __hip_bfloat16* W1 = (__hip_bfloat16*)(g_ws + OFF_W1);
  __hip_bfloat16* W2 = (__hip_bfloat16*)(g_ws + OFF_W2);
  if (fid < 294912) {            // Wo: (tap*256+oc)*128+ic
    int ic = fid & 127, rest = fid >> 7, oc = rest & 255, tap = rest >> 8;
    Wo[fid] = __float2bfloat16(offw[(oc * 128 + ic) * 9 + tap]);
  } else if (fid < 368640) {     // W1: (tap*64+oc)*128+ic
    int l = fid - 294912;
    int ic = l & 127, rest = l >> 7, oc = rest & 63, tap = rest >> 6;
    W1[l] = __float2bfloat16(c1w[(oc * 128 + ic) * 9 + tap]);
  } else if (fid < 405504) {     // W2: (tap*64+oc)*64+ic
    int l = fid - 368640;
    int ic = l & 63, rest = l >> 6, oc = rest & 63, tap = rest >> 6;
    W2[l] = __float2bfloat16(c2w[(oc * 64 + ic) * 9 + tap]);
  } else {
    int u = fid - 405504;
    if (u < 82432) halo_zero((short*)(g_ws + OFF_XCAT), 128, 4, u);
    else if (u < 164864) halo_zero((short*)(g_ws + OFF_XD), 128, 4, u - 82432);
    else halo_zero((short*)(g_ws + OFF_H1), 64, 3, u - 164864);
  }
}

// ---------- xpose: x2 NCHW f32 -> padded xcat NHWC bf16 lower 64 channels ----------
__global__ __launch_bounds__(256)
void k_xpose(const float* __restrict__ x2) {
  __shared__ short T[256][72];
  const int t = threadIdx.x;
  const int h = blockIdx.x & 255, b = blockIdx.x >> 8;
  const float* src = x2 + (size_t)(b * 64) * 65536 + h * 256;
  for (int rep = 0; rep < 64; ++rep) {
    int flat = rep * 256 + t, c = flat >> 8, w = flat & 255;
    T[w][c] = f2b(src[(size_t)c * 65536 + w]);
  }
  __syncthreads();
  short* xcat = (short*)(g_ws + OFF_XCAT) +
                (((size_t)(b * 258) + h + 1) * XROW + 1) * 128;
  for (int rep = 0; rep < 8; ++rep) {
    int unit = rep * 256 + t;  // w*8+cg
    int w = unit >> 3, cg = unit & 7;
    *(short8*)(xcat + (size_t)w * 128 + cg * 8) = *(short8*)(&T[w][cg * 8]);
  }
}

// ---------- upmfma: convT(2x2,s2) via 4 parity GEMMs -> padded xcat upper + XPU planar ----------
__global__ __launch_bounds__(256)
void k_upmfma(const float* __restrict__ x1, const float* __restrict__ up_w,
              const float* __restrict__ up_b) {
  __shared__ short W4[4][64][66];   // [k*2+l][o][i]
  __shared__ short X[64][68];       // [ws][i]
  __shared__ short U[2][128][66];   // [k][wl][o]
  __shared__ float BS[64];
  const int t = threadIdx.x;
  const int half = blockIdx.x & 1, hs = (blockIdx.x >> 1) & 127, b = blockIdx.x >> 8;
  for (int rep = 0; rep < 64; ++rep) {
    int flat = rep * 256 + t;
    int i = flat >> 8, rest = flat & 255, o = rest >> 2, kl = rest & 3;
    W4[kl][o][i] = f2b(up_w[flat]);
  }
  if (t < 64) BS[t] = up_b[t];
  const float* x1b = x1 + (size_t)(b * 64) * 16384 + hs * 128 + half * 64;
  for (int rep = 0; rep < 16; ++rep) {
    int flat = rep * 256 + t;
    int i = flat >> 6, ws = flat & 63;
    X[ws][i] = f2b(x1b[(size_t)i * 16384 + ws]);
  }
  __syncthreads();
  const int wv = t >> 6, lane = t & 63, l15 = lane & 15, quad = lane >> 4;
  short8 bf[2];
#pragma unroll
  for (int ks = 0; ks < 2; ++ks)
    bf[ks] = *(const short8*)(&X[wv * 16 + l15][ks * 32 + quad * 8]);
#pragma unroll
  for (int combo = 0; combo < 4; ++combo) {
    const int k = combo >> 1, l = combo & 1;
    f32x4 acc[4] = {};
#pragma unroll
    for (int nt = 0; nt < 4; ++nt)
#pragma unroll
      for (int ks = 0; ks < 2; ++ks) {
        short8 af = *(const short8*)(&W4[combo][nt * 16 + l15][ks * 32 + quad * 8]);
        acc[nt] = __builtin_amdgcn_mfma_f32_16x16x32_bf16(af, bf[ks], acc[nt], 0, 0, 0);
      }
    const int wl = 2 * (wv * 16 + l15) + l;
#pragma unroll
    for (int nt = 0; nt < 4; ++nt) {
      short4v s;
#pragma unroll
      for (int r = 0; r < 4; ++r) s[r] = f2b(acc[nt][r] + BS[nt * 16 + quad * 4 + r]);
      *(short4v*)(&U[k][wl][nt * 16 + quad * 4]) = s;
    }
  }
  __syncthreads();
  short* xcat = (short*)(g_ws + OFF_XCAT);
  short* xpu = (short*)(g_ws + OFF_XPU);
  for (int rep = 0; rep < 8; ++rep) {
    int unit = rep * 256 + t;
    int k = unit >> 10, wl = (unit >> 3) & 127, cg = unit & 7;
    int h = 2 * hs + k, w = half * 128 + wl;
    *(short8*)(xcat + (((size_t)(b * 258) + h + 1) * XROW + w + 1) * 128 + 64 + cg * 8) =
        *(short8*)(&U[k][wl][cg * 8]);
  }
  for (int rep = 0; rep < 8; ++rep) {
    int unit = rep * 256 + t;
    int o = unit >> 5, k = (unit >> 4) & 1, wg = unit & 15;
    int h = 2 * hs + k;
    short8 v;
#pragma unroll
    for (int j = 0; j < 8; ++j) v[j] = U[k][wg * 8 + j][o];
    *(short8*)(xpu + (size_t)(b * 64 + o) * 65536 + h * 256 + half * 128 + wg * 8) = v;
  }
}

// ---------- offconv: BOTH-operands-in-LDS implicit GEMM, 256px x 256oc (R6, 44% ceiling) ----------
__global__ __launch_bounds__(512, 2)
void k_offconv() {
  __shared__ short Bs[3 * 264 * 64];   // 101376 B
  __shared__ short As0[256 * 32];      // 16384 B
  __shared__ short As1[256 * 32];      // 16384 B
  const short* X = (const short*)(g_ws + OFF_XCAT);
  const __hip_bfloat16* W = (const __hip_bfloat16*)(g_ws + OFF_WO);
  const int t = threadIdx.x;
  const int vb = (int)((blockIdx.x & 7) * 64 + (blockIdx.x >> 3));  // bijective, 512%8==0
  const int h = vb & 255, b = vb >> 8;
  const int wid = t >> 6, lane = t & 63, l15 = lane & 15, quad = lane >> 4;
  const int ocbase = (wid & 1) * 128;
  const int pxb = (wid >> 1) * 64;
  const int lpx = lane >> 3, lcg = lane & 7;
  const short* bsrc = X + (((size_t)(b * 258) + h) * XROW + lpx) * 128 + (lcg ^ (lpx & 7)) * 8;
  const int loc = lane >> 2, lcg4 = lane & 3;
  const __hip_bfloat16* asrc = W + (size_t)loc * 128 + (lcg4 ^ ((loc + (loc >> 2)) & 3)) * 8;
  const int ax = (quad ^ ((l15 + (l15 >> 2)) & 3)) << 3;  // shorts
  const int abase = (ocbase + l15) * 32 + ax;
  f32x4 acc[8][4] = {};

#define STAGE_A(TAP, ICS, P, APTR)                                                  \
  {                                                                                 \
    _Pragma("unroll")                                                               \
    for (int k = 0; k < 2; ++k) {                                                   \
      int u = wid * 2 + k;                                                          \
      gload_lds16(asrc + ((size_t)(TAP) * 256 + u * 16) * 128 + (P) * 64 + (ICS) * 32, \
                  &APTR[u * 512]);                                                  \
    }                                                                               \
  }

  for (int p = 0; p < 2; ++p) {
    if (p) __syncthreads();
    for (int u = wid; u < 99; u += 8) {
      int r = u / 33, g = u - r * 33;
      gload_lds16(bsrc + (size_t)r * XRSH + g * 1024 + p * 64, &Bs[(r * 264 + g * 8) * 64]);
    }
    STAGE_A(0, 0, p, As0);
    STAGE_A(0, 1, p, As1);
    __syncthreads();
    for (int tap = 0; tap < 9; ++tap) {
      const int ky = tap / 3, kx = tap - 3 * ky;
      const short* srow = &Bs[(ky * 264 + pxb + l15 + kx) * 64];
      const int sx = ((l15 + kx) & 7) << 3;
      {  // ics = 0
        short8 a[8], bf[4];
#pragma unroll
        for (int ot = 0; ot < 8; ++ot) a[ot] = *(const short8*)(As0 + abase + ot * 512);
#pragma unroll
        for (int pt = 0; pt < 4; ++pt)
          bf[pt] = *(const short8*)(srow + pt * 1024 + ((quad * 8) ^ sx));
        __syncthreads();
        if (tap < 8) STAGE_A(tap + 1, 0, p, As0);
#pragma unroll
        for (int ot = 0; ot < 8; ++ot)
#pragma unroll
          for (int pt = 0; pt < 4; ++pt)
            acc[ot][pt] = __builtin_amdgcn_mfma_f32_16x16x32_bf16(a[ot], bf[pt], acc[ot][pt], 0, 0, 0);
      }
      {  // ics = 1
        short8 a[8], bf[4];
#pragma unroll
        for (int ot = 0; ot < 8; ++ot) a[ot] = *(const short8*)(As1 + abase + ot * 512);
#pragma unroll
        for (int pt = 0; pt < 4; ++pt)
          bf[pt] = *(const short8*)(srow + pt * 1024 + ((32 + quad * 8) ^ sx));
        __syncthreads();
        if (tap < 8) STAGE_A(tap + 1, 1, p, As1);
#pragma unroll
        for (int ot = 0; ot < 8; ++ot)
#pragma unroll
          for (int pt = 0; pt < 4; ++pt)
            acc[ot][pt] = __builtin_amdgcn_mfma_f32_16x16x32_bf16(a[ot], bf[pt], acc[ot][pt], 0, 0, 0);
      }
    }
  }
  __hip_bfloat16* out = (__hip_bfloat16*)(g_ws + OFF_OFF);  // NCHW (B,256,256,256)
#pragma unroll
  for (int ot = 0; ot < 8; ++ot)
#pragma unroll
    for (int pt = 0; pt < 4; ++pt)
#pragma unroll
      for (int r = 0; r < 4; ++r) {
        int oc = ocbase + ot * 16 + quad * 4 + r;
        int px = pxb + pt * 16 + l15;
        out[(((size_t)(b * 256 + oc)) * 256 + h) * 256 + px] =
            __float2bfloat16(acc[ot][pt][r]);
      }
#undef STAGE_A
}

// ---------- k_conv: LDS-staged implicit-GEMM 3x3 conv (OC=64) + bias + fused BN stats ----------
// Block = (b,h): 256 px x 64 oc, 256 threads / 4 waves; wave = 64px x 64oc
// (acc[4][4]=64 regs). K split into IC/32 phases of 32 ch.
// LDS 61 KB -> 2 blocks/CU. As is PING-PONG double-buffered (R7 race fix):
// per tap: issue restage(tap+1) into the idle buffer -> ds_read current ->
// 16 MFMA -> __syncthreads() (drains own vmcnt; restage visible to ALL waves
// before tap+1's reads — the offconv-proven barrier-spacing invariant).
// Bs: 3 rows x 272 px x 32 ch, XOR involution slot = chunk ^ ((px+(px>>2))&3)
// (2-way banked = free, m136); As: 64oc x 32ch, same involution over oc.
// Input X is PADDED (258x264) -> no bounds checks; cols >=264 staged as
// garbage but never read (max read col 257).
// Fused stats: per-lane px-sums -> shfl_xor over l15 -> LDS SB -> 1 atomic/ch.
template <int IC, int SO>
__global__ __launch_bounds__(256, 2)
void k_conv(size_t xoff, size_t woff, const float* __restrict__ bias, size_t ooff) {
  __shared__ short Bs[3 * 272 * 32];   // 52224 B
  __shared__ short As[2 * 2048];       // 8192 B (two 64oc x 32ch tiles)
  __shared__ float SB[128];
  const short* X = (const short*)(g_ws + xoff);
  const __hip_bfloat16* W = (const __hip_bfloat16*)(g_ws + woff);
  const int t = threadIdx.x;
  const int vb = (int)((blockIdx.x & 7) * 64 + (blockIdx.x >> 3));  // bijective, 512%8==0
  const int h = vb & 255, b = vb >> 8;
  const int wid = t >> 6, lane = t & 63, l15 = lane & 15, quad = lane >> 4;
  const int pxb = wid * 64;
  if (t < 128) SB[t] = 0.f;
  // staging lane map (shared by A and B): lane = lpx*4+lc; src chunk = lc^fl
  const int lpx = lane >> 2, lc = lane & 3;
  const int fl = (lpx + (lpx >> 2)) & 3;
  const short* bsrc = X + (((size_t)(b * 258) + h) * XROW + lpx) * IC + (lc ^ fl) * 8;
  const __hip_bfloat16* asrc = W + (size_t)lpx * IC + (lc ^ fl) * 8;
  const int aslot = (quad ^ ((l15 + (l15 >> 2)) & 3)) << 3;  // shorts
  f32x4 acc[4][4] = {};
  const int KP = IC / 32;
  for (int ph = 0; ph < KP; ++ph) {
    // safe to restage Bs/As[0]: first iter trivially; later iters follow the
    // end-of-tap-8 barrier (all reads of the previous phase complete).
    for (int u = wid; u < 51; u += 4) {      // B: 3 rows x 17 units of 16px x 32ch
      int r = u / 17, g = u - r * 17;
      gload_lds16(bsrc + ((size_t)r * XROW + g * 16) * IC + ph * 32,
                  &Bs[(r * 272 + g * 16) * 32]);
    }
    gload_lds16(asrc + (size_t)(wid * 16) * IC + ph * 32, &As[wid * 512]);  // tap 0 -> buf 0
    __syncthreads();          // drains own vmcnt -> Bs + As[0] ready for all
    for (int tap = 0; tap < 9; ++tap) {
      short* Ac = &As[(tap & 1) * 2048];
      short* An = &As[((tap & 1) ^ 1) * 2048];
      if (tap < 8)            // restage next tap into idle buffer (no reader yet)
        gload_lds16(asrc + ((size_t)((tap + 1) * 64) + wid * 16) * IC + ph * 32,
                    &An[wid * 512]);
      const int ky = tap / 3, kx = tap - 3 * ky;
      short8 a[4], bf[4];
#pragma unroll
      for (int ot = 0; ot < 4; ++ot)
        a[ot] = *(const short8*)(&Ac[(ot * 16 + l15) * 32 + aslot]);
      const int s = l15 + kx;
      const int bslot = (quad ^ ((s + (s >> 2)) & 3)) << 3;
#pragma unroll
      for (int pt = 0; pt < 4; ++pt)
        bf[pt] = *(const short8*)(&Bs[(ky * 272 + pxb + pt * 16 + s) * 32 + bslot]);
#pragma unroll
      for (int ot = 0; ot < 4; ++ot)
#pragma unroll
        for (int pt = 0; pt < 4; ++pt)
          acc[ot][pt] = __builtin_amdgcn_mfma_f32_16x16x32_bf16(a[ot], bf[pt], acc[ot][pt], 0, 0, 0);
      __syncthreads();        // own restage drained -> An ready for ALL waves
    }
  }
  // epilogue: bias + store NHWC + fused stats
  __hip_bfloat16* out = (__hip_bfloat16*)(g_ws + ooff);
#pragma unroll
  for (int ot = 0; ot < 4; ++ot) {
    const int oc0 = ot * 16 + quad * 4;
    float bv[4], sa[4] = {}, sa2[4] = {};
#pragma unroll
    for (int r = 0; r < 4; ++r) bv[r] = bias[oc0 + r];
#pragma unroll
    for (int pt = 0; pt < 4; ++pt) {
      const int px = pxb + pt * 16 + l15;
      short4v sv;
#pragma unroll
      for (int r = 0; r < 4; ++r) {
        float f = acc[ot][pt][r] + bv[r];
        sv[r] = f2b(f);
        sa[r] += f;
        sa2[r] = fmaf(f, f, sa2[r]);
      }
      *(short4v*)(out + ((((size_t)(b * 256) + h) * 256 + px) * 64 + oc0)) = sv;
    }
#pragma unroll
    for (int r = 0; r < 4; ++r) {
      float sv1 = sa[r], sv2 = sa2[r];
      for (int d = 1; d < 16; d <<= 1) {
        sv1 += __shfl_xor(sv1, d);
        sv2 += __shfl_xor(sv2, d);
      }
      if (l15 == 0) {
        atomicAdd(&SB[oc0 + r], sv1);
        atomicAdd(&SB[64 + oc0 + r], sv2);
      }
    }
  }
  __syncthreads();
  if (t < 128) atomicAdd(&g_st[SO + t], SB[t]);
}

// ---------- deform gather: channel-half per block -> PADDED xd ----------
__global__ __launch_bounds__(256, 4)
void k_gather(const float* __restrict__ x2) {
  __shared__ short G[256 * 66];   // 33792 B
  const __hip_bfloat16* off = (const __hip_bfloat16*)(g_ws + OFF_OFF);
  const __hip_bfloat16* xpu = (const __hip_bfloat16*)(g_ws + OFF_XPU);
  short* xd = (short*)(g_ws + OFF_XD);
  const int t = threadIdx.x;
  const int half = blockIdx.x & 1;
  const int hh = (blockIdx.x >> 1) & 255, b = blockIdx.x >> 9;
  const int hp = 2 * (hh & 127) + (t >> 7);
  const int w0e = 2 * (t & 127);
  const int chb = hh >> 7;
  const int c0 = half * 64;
  const float fh = (float)hh, fw = (float)t;
  const __hip_bfloat16* offb = off + ((size_t)(b * 256) * 256 + hp) * 256 + w0e +
                               (size_t)(2 * c0 + chb) * 65536;
  if (half == 0) {
    const float* x2b = x2 + (size_t)b * 64 * 65536;
    for (int g4 = 0; g4 < 16; ++g4) {
      unsigned ovv[4];
#pragma unroll
      for (int j = 0; j < 4; ++j)
        ovv[j] = *(const unsigned*)(offb + (size_t)(2 * (g4 * 4 + j)) * 65536);
#pragma unroll
      for (int j = 0; j < 4; ++j) {
        const int crel = g4 * 4 + j;
        unsigned ov = ovv[j];
        float oy = __uint_as_float((ov & 0xffffu) << 16);
        float ox = __uint_as_float((ov >> 16) << 16);
        float cy = fminf(fmaxf(oy + fh, 0.f), 255.f);
        float cx = fminf(fmaxf(ox + fw, 0.f), 255.f);
        float y0f = floorf(cy), x0f = floorf(cx);
        int y0 = (int)y0f, x0 = (int)x0f;
        int y1 = (int)ceilf(cy), x1 = (int)ceilf(cx);
        const float* pl = x2b + (size_t)crel * 65536;
        float v00 = pl[y0 * 256 + x0], v10 = pl[y1 * 256 + x0];
        float v01 = pl[y0 * 256 + x1], v11 = pl[y1 * 256 + x1];
        float wy = cy - y0f, wx = cx - x0f;
        float vt = v00 + (v10 - v00) * wy;
        float vb = v01 + (v11 - v01) * wy;
        G[t * 66 + crel] = f2b(vt + (vb - vt) * wx);
      }
    }
  } else {
    const __hip_bfloat16* xub = xpu + (size_t)b * 64 * 65536;
    for (int g4 = 0; g4 < 16; ++g4) {
      unsigned ovv[4];
#pragma unroll
      for (int j = 0; j < 4; ++j)
        ovv[j] = *(const unsigned*)(offb + (size_t)(2 * (g4 * 4 + j)) * 65536);
#pragma unroll
      for (int j = 0; j < 4; ++j) {
        const int crel = g4 * 4 + j;
        unsigned ov = ovv[j];
        float oy = __uint_as_float((ov & 0xffffu) << 16);
        float ox = __uint_as_float((ov >> 16) << 16);
        float cy = fminf(fmaxf(oy + fh, 0.f), 255.f);
        float cx = fminf(fmaxf(ox + fw, 0.f), 255.f);
        float y0f = floorf(cy), x0f = floorf(cx);
        int y0 = (int)y0f, x0 = (int)x0f;
        int y1 = (int)ceilf(cy), x1 = (int)ceilf(cx);
        const __hip_bfloat16* pl = xub + (size_t)crel * 65536;
        float v00 = b2f(pl[y0 * 256 + x0]), v10 = b2f(pl[y1 * 256 + x0]);
        float v01 = b2f(pl[y0 * 256 + x1]), v11 = b2f(pl[y1 * 256 + x1]);
        float wy = cy - y0f, wx = cx - x0f;
        float vt = v00 + (v10 - v00) * wy;
        float vb = v01 + (v11 - v01) * wy;
        G[t * 66 + crel] = f2b(vt + (vb - vt) * wx);
      }
    }
  }
  __syncthreads();
  const size_t dst = (((size_t)(b * 258) + hh + 1) * XROW + 1) * 128 + c0;
  for (int it = 0; it < 8; ++it) {
    int g = it * 256 + t;
    *(short8*)(xd + dst + (size_t)(g >> 3) * 128 + (g & 7) * 8) =
        *(short8*)(&G[(g >> 3) * 66 + (g & 7) * 8]);
  }
}

// ---------- BN apply + ReLU: c1o NHWC -> PADDED h1 NHWC bf16 (finstat folded) ----------
__global__ __launch_bounds__(256)
void k_bnrelu1(const float* __restrict__ g, const float* __restrict__ be) {
  __shared__ float A[64], Bc[64];
  const __hip_bfloat16* x = (const __hip_bfloat16*)(g_ws + OFF_C1O);
  short* o = (short*)(g_ws + OFF_H1);
  const int t = threadIdx.x;
  const int h = blockIdx.x & 255, b = blockIdx.x >> 8;
  if (t < 64) {
    float m = g_st[t] * (1.f / 131072.f);
    float v = g_st[64 + t] * (1.f / 131072.f) - m * m;
    float iv = rsqrtf(v + 1e-5f) * g[t];
    A[t] = iv;
    Bc[t] = be[t] - m * iv;
  }
  __syncthreads();
  const __hip_bfloat16* px = x + (((size_t)(b * 256) + h) * 256 + t) * 64;
  short* op = o + (((size_t)(b * 258) + h + 1) * XROW + t + 1) * 64;
#pragma unroll
  for (int cg = 0; cg < 8; ++cg) {
    short8 v = *(const short8*)(px + cg * 8);
    short8 r;
#pragma unroll
    for (int j = 0; j < 8; ++j) {
      int c = cg * 8 + j;
      r[j] = f2b(fmaxf(s2f(v[j]) * A[c] + Bc[c], 0.f));
    }
    *(short8*)(op + cg * 8) = r;
  }
}

// ---------- BN apply + ReLU + NHWC->NCHW f32 to d_out (finstat folded) ----------
__global__ __launch_bounds__(256)
void k_bnrelu2(const float* __restrict__ g, const float* __restrict__ be,
               float* __restrict__ dout) {
  __shared__ float T[64 * 257];
  __shared__ float A[64], Bc[64];
  const __hip_bfloat16* x = (const __hip_bfloat16*)(g_ws + OFF_C2O);
  const int t = threadIdx.x;
  const int h = blockIdx.x & 255, b = blockIdx.x >> 8;
  if (t < 64) {
    float m = g_st[128 + t] * (1.f / 131072.f);
    float v = g_st[192 + t] * (1.f / 131072.f) - m * m;
    float iv = rsqrtf(v + 1e-5f) * g[t];
    A[t] = iv;
    Bc[t] = be[t] - m * iv;
  }
  __syncthreads();
  const __hip_bfloat16* px = x + (((size_t)(b * 256) + h) * 256 + t) * 64;
#pragma unroll
  for (int cg = 0; cg < 8; ++cg) {
    short8 v = *(const short8*)(px + cg * 8);
#pragma unroll
    for (int j = 0; j < 8; ++j) {
      int c = cg * 8 + j;
      T[c * 257 + t] = fmaxf(s2f(v[j]) * A[c] + Bc[c], 0.f);
    }
  }
  __syncthreads();
  for (int rep = 0; rep < 64; ++rep) {
    int flat = rep * 256 + t, c = flat >> 8, w = flat & 255;
    dout[(((size_t)(b * 64 + c)) * 256 + h) * 256 + w] = T[c * 257 + w];
  }
}

extern "C" void kernel_launch(void* const* d_in, const int* in_sizes, int n_in,
                              void* d_out, int out_size, void* d_ws, size_t ws_size,
                              hipStream_t stream) {
  const bool ok = (n_in == 13) &&
                  in_sizes[0] == 2097152 && in_sizes[1] == 8388608 &&
                  in_sizes[2] == 16384 && in_sizes[3] == 64 &&
                  in_sizes[4] == 294912 && in_sizes[5] == 73728 &&
                  in_sizes[9] == 36864 && out_size == 8388608;
  if (!ok) { hipMemsetAsync(d_out, 0x46, (size_t)out_size * 2, stream); return; }

  const float* x1   = (const float*)d_in[0];
  const float* x2   = (const float*)d_in[1];
  const float* up_w = (const float*)d_in[2];
  const float* up_b = (const float*)d_in[3];
  const float* offw = (const float*)d_in[4];
  const float* c1w  = (const float*)d_in[5];
  const float* c1b  = (const float*)d_in[6];
  const float* g1   = (const float*)d_in[7];
  const float* b1   = (const float*)d_in[8];
  const float* c2w  = (const float*)d_in[9];
  const float* c2b  = (const float*)d_in[10];
  const float* g2   = (const float*)d_in[11];
  const float* b2   = (const float*)d_in[12];

  k_prep<<<2389, 256, 0, stream>>>(offw, c1w, c2w);
  k_xpose<<<512, 256, 0, stream>>>(x2);
  k_upmfma<<<512, 256, 0, stream>>>(x1, up_w, up_b);
  k_offconv<<<512, 512, 0, stream>>>();
  k_gather<<<1024, 256, 0, stream>>>(x2);
  k_conv<128, 0><<<512, 256, 0, stream>>>(OFF_XD, OFF_W1, c1b, OFF_C1O);
  k_bnrelu1<<<512, 256, 0, stream>>>(g1, b1);
  k_conv<64, 128><<<512, 256, 0, stream>>>(OFF_H1, OFF_W2, c2b, OFF_C2O);
  k_bnrelu2<<<512, 256, 0, stream>>>(g2, b2, (float*)d_out);

  (void)d_ws; (void)ws_size;
}